// Round 4
// baseline (9113.390 us; speedup 1.0000x reference)
//
#include <hip/hip_runtime.h>
#include <hip/hip_bf16.h>
#include <math.h>

typedef __hip_bfloat16 bf16;

#define BT   4096   // B*T rows
#define DM   1024
#define NH   16
#define DH   64
#define TSEQ 2048

__device__ __forceinline__ float wave_sum(float v){
#pragma unroll
  for (int o = 32; o; o >>= 1) v += __shfl_xor(v, o);
  return v;
}

__device__ __forceinline__ float block_sum(float v){
  __shared__ float sm[4];
  v = wave_sum(v);
  __syncthreads();                    // protect reuse across calls
  if ((threadIdx.x & 63) == 0) sm[threadIdx.x >> 6] = v;
  __syncthreads();
  return sm[0] + sm[1] + sm[2] + sm[3];
}

__device__ __forceinline__ float softplusf(float x){
  return x > 20.f ? x : log1pf(expf(x));
}

// ---------------- LayerNorm: one block per row of 1024 ----------------
__global__ __launch_bounds__(256) void ln_kernel(const float* __restrict__ xin,
    const float* __restrict__ g, const float* __restrict__ bb, float* __restrict__ out){
  const long row = blockIdx.x;
  const int tid = threadIdx.x;
  float v[4];
#pragma unroll
  for (int i = 0; i < 4; i++) v[i] = xin[row * DM + tid + i * 256];
  float s = block_sum(v[0] + v[1] + v[2] + v[3]);
  const float mu = s * (1.f / DM);
  float d2 = 0.f;
#pragma unroll
  for (int i = 0; i < 4; i++){ float dd = v[i] - mu; d2 = fmaf(dd, dd, d2); }
  d2 = block_sum(d2);
  const float rstd = rsqrtf(d2 * (1.f / DM) + 1e-5f);
#pragma unroll
  for (int i = 0; i < 4; i++){
    int c = tid + i * 256;
    out[row * DM + c] = fmaf((v[i] - mu) * rstd, g[c], bb[c]);
  }
}

// ---------------- Generic f32 GEMM: C[M,N] = A[M,K] @ W[K,N] (+epilogue) --------
// EPI: 0 none | 1 +bias | 2 +bias+f32 residual | 3 +bias,GELU | 4 +bias+f32 residual
template <int EPI>
__global__ __launch_bounds__(256) void gemm_kernel(
    const float* __restrict__ A, const float* __restrict__ W,
    const float* __restrict__ bias, const float* __restrict__ resf,
    float* __restrict__ Cf, int M, int N, int K)
{
  __shared__ float As[16][65];
  __shared__ float Bs[16][65];
  const int tid = threadIdx.x;
  const int bm0 = blockIdx.y << 6, bn0 = blockIdx.x << 6;
  const int ar = tid >> 2, ac = (tid & 3) << 2;   // A tile loader: 64 rows x 16 cols
  const int wr = tid >> 4, wc = (tid & 15) << 2;  // W tile loader: 16 rows x 64 cols
  const int tx = tid & 15, ty = tid >> 4;
  float acc[4][4] = {};
  for (int k0 = 0; k0 < K; k0 += 16){
    const float4 av = *(const float4*)(A + (long)(bm0 + ar) * K + (k0 + ac));
    As[ac + 0][ar] = av.x; As[ac + 1][ar] = av.y;
    As[ac + 2][ar] = av.z; As[ac + 3][ar] = av.w;
#pragma unroll
    for (int i = 0; i < 4; i++){
      int col = bn0 + wc + i;
      Bs[wr][wc + i] = (col < N) ? W[(long)(k0 + wr) * N + col] : 0.f;
    }
    __syncthreads();
#pragma unroll
    for (int k = 0; k < 16; k++){
      float a[4], b[4];
#pragma unroll
      for (int i = 0; i < 4; i++) a[i] = As[k][(ty << 2) + i];
#pragma unroll
      for (int j = 0; j < 4; j++) b[j] = Bs[k][(tx << 2) + j];
#pragma unroll
      for (int i = 0; i < 4; i++)
#pragma unroll
        for (int j = 0; j < 4; j++)
          acc[i][j] = fmaf(a[i], b[j], acc[i][j]);
    }
    __syncthreads();
  }
#pragma unroll
  for (int i = 0; i < 4; i++){
    const int row = bm0 + (ty << 2) + i;
#pragma unroll
    for (int j = 0; j < 4; j++){
      const int col = bn0 + (tx << 2) + j;
      if (col >= N) continue;
      float v = acc[i][j];
      const long off = (long)row * N + col;
      if constexpr (EPI >= 1) v += bias[col];
      if constexpr (EPI == 2 || EPI == 4) v += resf[off];
      if constexpr (EPI == 3) v = 0.5f * v * (1.f + erff(v * 0.70710678118654752f));
      Cf[off] = v;
    }
  }
}

// ---------------- l2norm + RoPE, one wave per (b,t,h) row of 64 ----------------
__global__ __launch_bounds__(256) void qkprep_kernel(float* __restrict__ Qb, float* __restrict__ Kb){
  const int lane = threadIdx.x & 63;
  const long row = ((long)blockIdx.x << 2) + (threadIdx.x >> 6);  // < B*T*H
  const int t = (int)((row >> 4) & (TSEQ - 1));
  const long base = (row << 6) + lane;
  const float freq = expf(-(float)(lane >> 1) * 0.28782313662425575f); // ln(1e4)/32
  const float th = (float)t * freq;
  const float sn = sinf(th), cn = cosf(th);
  {
    float q = Qb[base];
    float n = sqrtf(wave_sum(q * q));
    q = q / fmaxf(n, 1e-12f);
    float pr = __shfl_xor(q, 1);
    Qb[base] = (lane & 1) ? fmaf(pr, sn, q * cn) : fmaf(q, cn, -pr * sn);
  }
  {
    float k = Kb[base];
    float n = sqrtf(wave_sum(k * k));
    k = k / fmaxf(n, 1e-12f);
    float pr = __shfl_xor(k, 1);
    Kb[base] = (lane & 1) ? fmaf(pr, sn, k * cn) : fmaf(k, cn, -pr * sn);
  }
}

// ---------------- Chunked scans over T (32 chunks x 64) ----------------
// chain = (b*NH+h)*64+d ; thread layout tid = ((bh*32)+chunk)*64 + d  (d fastest)
__global__ __launch_bounds__(256) void scan_p1(float* __restrict__ G, const float* __restrict__ P,
    float* __restrict__ cmax, float* __restrict__ gsum){
  const int tid = blockIdx.x * 256 + threadIdx.x;    // 65536
  const int d = tid & 63, c = (tid >> 6) & 31, bh = tid >> 11;
  const int h = bh & 15, b = bh >> 4;
  const long base = (((long)(b * TSEQ + c * 64)) * NH + h) * 64 + d;
  float mx = -1e30f, gs = 0.f;
  for (int tt = 0; tt < 64; tt++){
    const long idx = base + (long)tt * (NH * 64);
    float gj = -softplusf(G[idx]);
    G[idx] = gj;
    gs += gj;
    mx = fmaxf(mx, P[idx]);
  }
  const int chain = bh * 64 + d;
  cmax[chain * 32 + c] = mx;
  gsum[chain * 32 + c] = gs;
}

__global__ void scan_p2(const float* __restrict__ cmax, const float* __restrict__ gsum,
                        float* __restrict__ pmax, float* __restrict__ gpre){
  const int chain = blockIdx.x * 256 + threadIdx.x;  // 2048
  float mx = -1e30f;
  for (int c = 0; c < 32; c++) mx = fmaxf(mx, cmax[chain * 32 + c]);
  pmax[chain] = mx;
  float run = 0.f;
  for (int c = 0; c < 32; c++){ gpre[chain * 32 + c] = run; run += gsum[chain * 32 + c]; }
}

__global__ __launch_bounds__(256) void scan_p3(const float* __restrict__ G, float* __restrict__ P,
    const float* __restrict__ CLKr, float* __restrict__ Q, float* __restrict__ K,
    const float* __restrict__ pmax, const float* __restrict__ gpre, float* __restrict__ psum){
  const int tid = blockIdx.x * 256 + threadIdx.x;
  const int d = tid & 63, c = (tid >> 6) & 31, bh = tid >> 11;
  const int h = bh & 15, b = bh >> 4;
  const int chain = bh * 64 + d;
  const long base = (((long)(b * TSEQ + c * 64)) * NH + h) * 64 + d;
  const float pm = pmax[chain];
  float grun = gpre[chain * 32 + c];
  float ps = 0.f;
  for (int tt = 0; tt < 64; tt++){
    const long idx = base + (long)tt * (NH * 64);
    const int t = c * 64 + tt;
    float clk = softplusf(CLKr[(long)(b * TSEQ + t) * NH + h]);
    float pe = expf(P[idx] - pm) * clk;
    P[idx] = pe; ps += pe;
    grun += G[idx];                                   // gj (inclusive cumsum)
    float gc = expf(fminf(fmaxf(grun, -60.f), 50.f)); // gcp
    Q[idx] *= gc;
    K[idx] = K[idx] / (gc + 1e-8f);
  }
  psum[chain * 32 + c] = ps;
}

__global__ void scan_p4(const float* __restrict__ psum, float* __restrict__ ppre){
  const int chain = blockIdx.x * 256 + threadIdx.x;
  float run = 0.f;
  for (int c = 0; c < 32; c++){ ppre[chain * 32 + c] = run; run += psum[chain * 32 + c]; }
}

__global__ __launch_bounds__(256) void scan_p5(const float* __restrict__ P, float* __restrict__ Q,
    float* __restrict__ K, const float* __restrict__ ppre){
  const int tid = blockIdx.x * 256 + threadIdx.x;
  const int d = tid & 63, c = (tid >> 6) & 31, bh = tid >> 11;
  const int h = bh & 15, b = bh >> 4;
  const int chain = bh * 64 + d;
  const long base = (((long)(b * TSEQ + c * 64)) * NH + h) * 64 + d;
  float cs = ppre[chain * 32 + c];
  for (int tt = 0; tt < 64; tt++){
    const long idx = base + (long)tt * (NH * 64);
    float pe = P[idx];
    cs += pe;                      // inclusive cumsum
    Q[idx] = Q[idx] / (cs + 1e-8f);
    K[idx] *= pe;
  }
}

// ---------------- Causal attention, online softmax, 1 wave = 4 queries ----------------
__global__ __launch_bounds__(256) void attn_kernel(const float* __restrict__ Q,
    const float* __restrict__ K, const float* __restrict__ V, float* __restrict__ O){
  const int lane = threadIdx.x & 63;
  const long wid = ((long)blockIdx.x << 2) + (threadIdx.x >> 6);  // 16384 waves
  const int tb = (int)(wid & (TSEQ / 4 - 1));
  const int bh = (int)(wid >> 9);
  const int h = bh & 15, b = bh >> 4;
  const int t0 = tb << 2;
  const long stride = NH * DH;  // 1024
  const long qbase = ((long)(b * TSEQ + t0) * NH + h) * 64 + lane;
  const float q0 = Q[qbase], q1 = Q[qbase + stride], q2 = Q[qbase + 2 * stride], q3 = Q[qbase + 3 * stride];
  const long kb = ((long)b * TSEQ * NH + h) * 64 + lane;
  float m0 = -1e30f, m1 = -1e30f, m2 = -1e30f, m3 = -1e30f;
  float l0 = 0, l1 = 0, l2 = 0, l3 = 0, o0 = 0, o1 = 0, o2 = 0, o3 = 0;
  for (int j = 0; j <= t0 + 3; j++){
    const long off = kb + (long)j * stride;
    const float kv = K[off];
    const float vv = V[off];
    float s0 = q0 * kv, s1 = q1 * kv, s2 = q2 * kv, s3 = q3 * kv;
#pragma unroll
    for (int o = 32; o; o >>= 1){
      s0 += __shfl_xor(s0, o);
      s1 += __shfl_xor(s1, o);
      s2 += __shfl_xor(s2, o);
      s3 += __shfl_xor(s3, o);
    }
    s0 *= 0.125f; s1 *= 0.125f; s2 *= 0.125f; s3 *= 0.125f;
    if (j > t0)     s0 = -1e30f;
    if (j > t0 + 1) s1 = -1e30f;
    if (j > t0 + 2) s2 = -1e30f;
    { float mn = fmaxf(m0, s0), sc = __expf(m0 - mn), p = __expf(s0 - mn); l0 = l0 * sc + p; o0 = fmaf(p, vv, o0 * sc); m0 = mn; }
    { float mn = fmaxf(m1, s1), sc = __expf(m1 - mn), p = __expf(s1 - mn); l1 = l1 * sc + p; o1 = fmaf(p, vv, o1 * sc); m1 = mn; }
    { float mn = fmaxf(m2, s2), sc = __expf(m2 - mn), p = __expf(s2 - mn); l2 = l2 * sc + p; o2 = fmaf(p, vv, o2 * sc); m2 = mn; }
    { float mn = fmaxf(m3, s3), sc = __expf(m3 - mn), p = __expf(s3 - mn); l3 = l3 * sc + p; o3 = fmaf(p, vv, o3 * sc); m3 = mn; }
  }
  O[qbase] = o0 / l0;
  O[qbase + stride] = o1 / l1;
  O[qbase + 2 * stride] = o2 / l2;
  O[qbase + 3 * stride] = o3 / l3;
}

extern "C" void kernel_launch(void* const* d_in, const int* in_sizes, int n_in,
                              void* d_out, int out_size, void* d_ws, size_t ws_size,
                              hipStream_t stream){
  const float* x       = (const float*)d_in[0];
  const float* Wq      = (const float*)d_in[1];
  const float* Wk      = (const float*)d_in[2];
  const float* Wv      = (const float*)d_in[3];
  const float* gate_w  = (const float*)d_in[4];
  const float* gate_b  = (const float*)d_in[5];
  const float* p_w     = (const float*)d_in[6];
  const float* p_b     = (const float*)d_in[7];
  const float* out_w   = (const float*)d_in[8];
  const float* out_b   = (const float*)d_in[9];
  const float* clock_w = (const float*)d_in[10];
  const float* clock_b = (const float*)d_in[11];
  const float* ln1_g   = (const float*)d_in[12];
  const float* ln1_b   = (const float*)d_in[13];
  const float* ln2_g   = (const float*)d_in[14];
  const float* ln2_b   = (const float*)d_in[15];
  const float* mlp_w1  = (const float*)d_in[16];
  const float* mlp_b1  = (const float*)d_in[17];
  const float* mlp_w2  = (const float*)d_in[18];
  const float* mlp_b2  = (const float*)d_in[19];
  float* outp = (float*)d_out;   // reference output dtype is float32

  // workspace layout (floats); total ~25.43M floats ~= 97 MiB
  float* ws   = (float*)d_ws;
  float* XN   = ws;             // 4M  (xn; later H = LN2 out)
  float* Qb   = ws + 4194304;   // 4M
  float* Kb   = ws + 8388608;   // 4M
  float* Vb   = ws + 12582912;  // 4M
  float* Gb   = ws + 16777216;  // 4M  (gate raw -> gj; later O = attn out)
  float* Pb   = ws + 20971520;  // 4M  (p raw -> p_exp; later X1)
  float* CLKr = ws + 25165824;  // 64K (clock raw)
  float* cmax = ws + 25231360;  // 64K
  float* gsum = cmax + 65536;   // 64K (later psum)
  float* gpre = gsum + 65536;   // 64K (later ppre)
  float* pmax = gpre + 65536;   // 2K
  float* MID  = Qb;             // 16M, overlays dead Q/K/V/G at MLP time
  float* X1   = Pb;
  float* O    = Gb;
  float* H    = XN;

  ln_kernel<<<BT, 256, 0, stream>>>(x, ln1_g, ln1_b, XN);

  dim3 gD((DM + 63) / 64, BT / 64);
  gemm_kernel<0><<<gD, 256, 0, stream>>>(XN, Wq, nullptr, nullptr, Qb, BT, DM, DM);
  gemm_kernel<0><<<gD, 256, 0, stream>>>(XN, Wk, nullptr, nullptr, Kb, BT, DM, DM);
  gemm_kernel<0><<<gD, 256, 0, stream>>>(XN, Wv, nullptr, nullptr, Vb, BT, DM, DM);
  gemm_kernel<1><<<gD, 256, 0, stream>>>(XN, gate_w, gate_b, nullptr, Gb, BT, DM, DM);
  gemm_kernel<1><<<gD, 256, 0, stream>>>(XN, p_w, p_b, nullptr, Pb, BT, DM, DM);
  dim3 gC(1, BT / 64);
  gemm_kernel<1><<<gC, 256, 0, stream>>>(XN, clock_w, clock_b, nullptr, CLKr, BT, NH, DM);

  qkprep_kernel<<<16384, 256, 0, stream>>>(Qb, Kb);

  scan_p1<<<256, 256, 0, stream>>>(Gb, Pb, cmax, gsum);
  scan_p2<<<8, 256, 0, stream>>>(cmax, gsum, pmax, gpre);
  scan_p3<<<256, 256, 0, stream>>>(Gb, Pb, CLKr, Qb, Kb, pmax, gpre, gsum);
  scan_p4<<<8, 256, 0, stream>>>(gsum, gpre);
  scan_p5<<<256, 256, 0, stream>>>(Pb, Qb, Kb, gpre);

  attn_kernel<<<4096, 256, 0, stream>>>(Qb, Kb, Vb, O);

  gemm_kernel<2><<<gD, 256, 0, stream>>>(O, out_w, out_b, x, X1, BT, DM, DM);
  ln_kernel<<<BT, 256, 0, stream>>>(X1, ln2_g, ln2_b, H);
  dim3 gM1((4 * DM + 63) / 64, BT / 64);
  gemm_kernel<3><<<gM1, 256, 0, stream>>>(H, mlp_w1, mlp_b1, nullptr, MID, BT, 4 * DM, DM);
  gemm_kernel<4><<<gD, 256, 0, stream>>>(MID, mlp_w2, mlp_b2, X1, outp, BT, DM, 4 * DM);
}

// Round 5
// 3131.405 us; speedup vs baseline: 2.9103x; 2.9103x over previous
//
#include <hip/hip_runtime.h>
#include <hip/hip_bf16.h>
#include <math.h>

typedef __hip_bfloat16 bf16;
typedef __attribute__((ext_vector_type(8))) short short8;
typedef __attribute__((ext_vector_type(4))) short short4v;
typedef __attribute__((ext_vector_type(4))) float f32x4;

#define BT   4096   // B*T rows
#define DM   1024
#define NH   16
#define DH   64
#define TSEQ 2048

__device__ __forceinline__ float wave_sum(float v){
#pragma unroll
  for (int o = 32; o; o >>= 1) v += __shfl_xor(v, o);
  return v;
}

__device__ __forceinline__ float block_sum(float v){
  __shared__ float sm[4];
  v = wave_sum(v);
  __syncthreads();                    // protect reuse across calls
  if ((threadIdx.x & 63) == 0) sm[threadIdx.x >> 6] = v;
  __syncthreads();
  return sm[0] + sm[1] + sm[2] + sm[3];
}

__device__ __forceinline__ float softplusf(float x){
  return x > 20.f ? x : log1pf(expf(x));
}

__device__ __forceinline__ short f2bf(float f){
  unsigned u = __builtin_bit_cast(unsigned, f);
  u += 0x7FFF + ((u >> 16) & 1);          // RNE; inputs finite
  return (short)(u >> 16);
}

__device__ __forceinline__ short8 ld8(const short* p){  // two 8B-aligned LDS reads
  short4v a = *(const short4v*)p;
  short4v b = *(const short4v*)(p + 4);
  short8 r;
  r[0]=a[0]; r[1]=a[1]; r[2]=a[2]; r[3]=a[3];
  r[4]=b[0]; r[5]=b[1]; r[6]=b[2]; r[7]=b[3];
  return r;
}

// ---------------- LayerNorm: one block per row of 1024 ----------------
__global__ __launch_bounds__(256) void ln_kernel(const float* __restrict__ xin,
    const float* __restrict__ g, const float* __restrict__ bb, float* __restrict__ out){
  const long row = blockIdx.x;
  const int tid = threadIdx.x;
  float v[4];
#pragma unroll
  for (int i = 0; i < 4; i++) v[i] = xin[row * DM + tid + i * 256];
  float s = block_sum(v[0] + v[1] + v[2] + v[3]);
  const float mu = s * (1.f / DM);
  float d2 = 0.f;
#pragma unroll
  for (int i = 0; i < 4; i++){ float dd = v[i] - mu; d2 = fmaf(dd, dd, d2); }
  d2 = block_sum(d2);
  const float rstd = rsqrtf(d2 * (1.f / DM) + 1e-5f);
#pragma unroll
  for (int i = 0; i < 4; i++){
    int c = tid + i * 256;
    out[row * DM + c] = fmaf((v[i] - mu) * rstd, g[c], bb[c]);
  }
}

// ---------------- Generic f32 GEMM: C[M,N] = A[M,K] @ W[K,N] (+epilogue) --------
// EPI: 0 none | 1 +bias | 2 +bias+f32 residual | 3 +bias,GELU | 4 +bias+f32 residual
template <int EPI>
__global__ __launch_bounds__(256) void gemm_kernel(
    const float* __restrict__ A, const float* __restrict__ W,
    const float* __restrict__ bias, const float* __restrict__ resf,
    float* __restrict__ Cf, int M, int N, int K)
{
  __shared__ float As[16][65];
  __shared__ float Bs[16][65];
  const int tid = threadIdx.x;
  const int bm0 = blockIdx.y << 6, bn0 = blockIdx.x << 6;
  const int ar = tid >> 2, ac = (tid & 3) << 2;   // A tile loader: 64 rows x 16 cols
  const int wr = tid >> 4, wc = (tid & 15) << 2;  // W tile loader: 16 rows x 64 cols
  const int tx = tid & 15, ty = tid >> 4;
  float acc[4][4] = {};
  for (int k0 = 0; k0 < K; k0 += 16){
    const float4 av = *(const float4*)(A + (long)(bm0 + ar) * K + (k0 + ac));
    As[ac + 0][ar] = av.x; As[ac + 1][ar] = av.y;
    As[ac + 2][ar] = av.z; As[ac + 3][ar] = av.w;
#pragma unroll
    for (int i = 0; i < 4; i++){
      int col = bn0 + wc + i;
      Bs[wr][wc + i] = (col < N) ? W[(long)(k0 + wr) * N + col] : 0.f;
    }
    __syncthreads();
#pragma unroll
    for (int k = 0; k < 16; k++){
      float a[4], b[4];
#pragma unroll
      for (int i = 0; i < 4; i++) a[i] = As[k][(ty << 2) + i];
#pragma unroll
      for (int j = 0; j < 4; j++) b[j] = Bs[k][(tx << 2) + j];
#pragma unroll
      for (int i = 0; i < 4; i++)
#pragma unroll
        for (int j = 0; j < 4; j++)
          acc[i][j] = fmaf(a[i], b[j], acc[i][j]);
    }
    __syncthreads();
  }
#pragma unroll
  for (int i = 0; i < 4; i++){
    const int row = bm0 + (ty << 2) + i;
#pragma unroll
    for (int j = 0; j < 4; j++){
      const int col = bn0 + (tx << 2) + j;
      if (col >= N) continue;
      float v = acc[i][j];
      const long off = (long)row * N + col;
      if constexpr (EPI >= 1) v += bias[col];
      if constexpr (EPI == 2 || EPI == 4) v += resf[off];
      if constexpr (EPI == 3) v = 0.5f * v * (1.f + erff(v * 0.70710678118654752f));
      Cf[off] = v;
    }
  }
}

// ---------------- l2norm + RoPE, one wave per (b,t,h) row of 64 ----------------
__global__ __launch_bounds__(256) void qkprep_kernel(float* __restrict__ Qb, float* __restrict__ Kb){
  const int lane = threadIdx.x & 63;
  const long row = ((long)blockIdx.x << 2) + (threadIdx.x >> 6);  // < B*T*H
  const int t = (int)((row >> 4) & (TSEQ - 1));
  const long base = (row << 6) + lane;
  const float freq = expf(-(float)(lane >> 1) * 0.28782313662425575f); // ln(1e4)/32
  const float th = (float)t * freq;
  const float sn = sinf(th), cn = cosf(th);
  {
    float q = Qb[base];
    float n = sqrtf(wave_sum(q * q));
    q = q / fmaxf(n, 1e-12f);
    float pr = __shfl_xor(q, 1);
    Qb[base] = (lane & 1) ? fmaf(pr, sn, q * cn) : fmaf(q, cn, -pr * sn);
  }
  {
    float k = Kb[base];
    float n = sqrtf(wave_sum(k * k));
    k = k / fmaxf(n, 1e-12f);
    float pr = __shfl_xor(k, 1);
    Kb[base] = (lane & 1) ? fmaf(pr, sn, k * cn) : fmaf(k, cn, -pr * sn);
  }
}

// ---------------- Chunked scans over T (32 chunks x 64) ----------------
// chain = (b*NH+h)*64+d ; thread layout tid = ((bh*32)+chunk)*64 + d  (d fastest)
__global__ __launch_bounds__(256) void scan_p1(float* __restrict__ G, const float* __restrict__ P,
    float* __restrict__ cmax, float* __restrict__ gsum){
  const int tid = blockIdx.x * 256 + threadIdx.x;    // 65536
  const int d = tid & 63, c = (tid >> 6) & 31, bh = tid >> 11;
  const int h = bh & 15, b = bh >> 4;
  const long base = (((long)(b * TSEQ + c * 64)) * NH + h) * 64 + d;
  float mx = -1e30f, gs = 0.f;
  for (int tt = 0; tt < 64; tt++){
    const long idx = base + (long)tt * (NH * 64);
    float gj = -softplusf(G[idx]);
    G[idx] = gj;
    gs += gj;
    mx = fmaxf(mx, P[idx]);
  }
  const int chain = bh * 64 + d;
  cmax[chain * 32 + c] = mx;
  gsum[chain * 32 + c] = gs;
}

__global__ void scan_p2(const float* __restrict__ cmax, const float* __restrict__ gsum,
                        float* __restrict__ pmax, float* __restrict__ gpre){
  const int chain = blockIdx.x * 256 + threadIdx.x;  // 2048
  float mx = -1e30f;
  for (int c = 0; c < 32; c++) mx = fmaxf(mx, cmax[chain * 32 + c]);
  pmax[chain] = mx;
  float run = 0.f;
  for (int c = 0; c < 32; c++){ gpre[chain * 32 + c] = run; run += gsum[chain * 32 + c]; }
}

__global__ __launch_bounds__(256) void scan_p3(const float* __restrict__ G, float* __restrict__ P,
    const float* __restrict__ CLKr, float* __restrict__ Q, float* __restrict__ K,
    const float* __restrict__ pmax, const float* __restrict__ gpre, float* __restrict__ psum){
  const int tid = blockIdx.x * 256 + threadIdx.x;
  const int d = tid & 63, c = (tid >> 6) & 31, bh = tid >> 11;
  const int h = bh & 15, b = bh >> 4;
  const int chain = bh * 64 + d;
  const long base = (((long)(b * TSEQ + c * 64)) * NH + h) * 64 + d;
  const float pm = pmax[chain];
  float grun = gpre[chain * 32 + c];
  float ps = 0.f;
  for (int tt = 0; tt < 64; tt++){
    const long idx = base + (long)tt * (NH * 64);
    const int t = c * 64 + tt;
    float clk = softplusf(CLKr[(long)(b * TSEQ + t) * NH + h]);
    float pe = expf(P[idx] - pm) * clk;
    P[idx] = pe; ps += pe;
    grun += G[idx];                                   // gj (inclusive cumsum)
    float gc = expf(fminf(fmaxf(grun, -60.f), 50.f)); // gcp
    Q[idx] *= gc;
    K[idx] = K[idx] / (gc + 1e-8f);
  }
  psum[chain * 32 + c] = ps;
}

__global__ void scan_p4(const float* __restrict__ psum, float* __restrict__ ppre){
  const int chain = blockIdx.x * 256 + threadIdx.x;
  float run = 0.f;
  for (int c = 0; c < 32; c++){ ppre[chain * 32 + c] = run; run += psum[chain * 32 + c]; }
}

__global__ __launch_bounds__(256) void scan_p5(const float* __restrict__ P, float* __restrict__ Q,
    float* __restrict__ K, const float* __restrict__ ppre){
  const int tid = blockIdx.x * 256 + threadIdx.x;
  const int d = tid & 63, c = (tid >> 6) & 31, bh = tid >> 11;
  const int h = bh & 15, b = bh >> 4;
  const int chain = bh * 64 + d;
  const long base = (((long)(b * TSEQ + c * 64)) * NH + h) * 64 + d;
  float cs = ppre[chain * 32 + c];
  for (int tt = 0; tt < 64; tt++){
    const long idx = base + (long)tt * (NH * 64);
    float pe = P[idx];
    cs += pe;                      // inclusive cumsum
    Q[idx] = Q[idx] / (cs + 1e-8f);
    K[idx] *= pe;
  }
}

// ---------------- MFMA flash attention ----------------
// block = 64 queries of one (b,h); 4 waves x 16 queries; K-tiles of 32 keys.
// mfma_f32_16x16x32_bf16 layouts (m89/m120-verified):
//   A[m=lane&15][k=quad*8+j], B[k=quad*8+j][n=lane&15], C/D: col=lane&15, row=quad*4+reg
__global__ __launch_bounds__(256) void fattn_kernel(const float* __restrict__ Q,
    const float* __restrict__ K, const float* __restrict__ V, float* __restrict__ O){
  __shared__ __attribute__((aligned(16))) short Ks[32][72];   // [key][d], pad 64->72 (2-way free)
  __shared__ __attribute__((aligned(16))) short Vt[64][36];   // [d][key], pad 32->36 (conflict-free)
  __shared__ __attribute__((aligned(16))) short Ps[4][16][40];// per-wave P, pad 32->40 (2-way free)
  const int tid  = threadIdx.x;
  const int lane = tid & 63, w = tid >> 6;
  const int quad = lane >> 4, l16 = lane & 15;
  const int bh = blockIdx.y, h = bh & 15, b = bh >> 4;
  const int q0  = blockIdx.x << 6;
  const int qw0 = q0 + w * 16;
  const long strideT = NH * DH;                         // 1024
  const long base_bh = ((long)b * TSEQ * NH + h) * DH;  // (b, t=0, h, d=0)

  // Q fragments (scaled by 1/sqrt(Dh)=0.125, exact in bf16)
  short8 qa0, qa1;
  {
    const float* qp = Q + base_bh + (long)(qw0 + l16) * strideT + quad * 8;
#pragma unroll
    for (int j = 0; j < 8; j++) qa0[j] = f2bf(qp[j] * 0.125f);
#pragma unroll
    for (int j = 0; j < 8; j++) qa1[j] = f2bf(qp[32 + j] * 0.125f);
  }

  f32x4 oacc[4] = {{0,0,0,0},{0,0,0,0},{0,0,0,0},{0,0,0,0}};
  float m[4]    = {-1e30f,-1e30f,-1e30f,-1e30f};
  float lsum[4] = {0.f,0.f,0.f,0.f};

  const int ntiles = (q0 >> 5) + 2;
  const int kkey = tid >> 3;            // staging: key 0..31
  const int kd   = (tid & 7) << 3;      // staging: d 0,8,...,56

  for (int t = 0; t < ntiles; t++){
    const int kt0 = t << 5;
    // ---- stage K (row-major bf16) and V (transposed bf16) ----
    {
      const long krow = base_bh + (long)(kt0 + kkey) * strideT + kd;
      const float* kp = K + krow;
      short8 kv;
#pragma unroll
      for (int j = 0; j < 8; j++) kv[j] = f2bf(kp[j]);
      *(short8*)&Ks[kkey][kd] = kv;
      const float* vp = V + krow;
#pragma unroll
      for (int j = 0; j < 8; j++) Vt[kd + j][kkey] = f2bf(vp[j]);
    }
    __syncthreads();
    if (kt0 <= qw0 + 15){
      // ---- S = Q K^T (two 16x16 tiles over 32 keys) ----
      f32x4 c0 = {0,0,0,0}, c1 = {0,0,0,0};
      {
        short8 kb00 = ld8(&Ks[l16][quad * 8]);
        short8 kb01 = ld8(&Ks[l16][32 + quad * 8]);
        short8 kb10 = ld8(&Ks[16 + l16][quad * 8]);
        short8 kb11 = ld8(&Ks[16 + l16][32 + quad * 8]);
        c0 = __builtin_amdgcn_mfma_f32_16x16x32_bf16(qa0, kb00, c0, 0, 0, 0);
        c0 = __builtin_amdgcn_mfma_f32_16x16x32_bf16(qa1, kb01, c0, 0, 0, 0);
        c1 = __builtin_amdgcn_mfma_f32_16x16x32_bf16(qa0, kb10, c1, 0, 0, 0);
        c1 = __builtin_amdgcn_mfma_f32_16x16x32_bf16(qa1, kb11, c1, 0, 0, 0);
      }
      // ---- causal mask (wave-uniform diagonal tiles only) ----
      if (kt0 + 31 > qw0){
#pragma unroll
        for (int r = 0; r < 4; r++){
          const int q = qw0 + quad * 4 + r;
          if (kt0 + l16 > q)      c0[r] = -1e30f;
          if (kt0 + 16 + l16 > q) c1[r] = -1e30f;
        }
      }
      // ---- online softmax ----
      float tmax[4], alpha[4];
#pragma unroll
      for (int r = 0; r < 4; r++) tmax[r] = fmaxf(c0[r], c1[r]);
#pragma unroll
      for (int o = 1; o <= 8; o <<= 1)
#pragma unroll
        for (int r = 0; r < 4; r++) tmax[r] = fmaxf(tmax[r], __shfl_xor(tmax[r], o));
#pragma unroll
      for (int r = 0; r < 4; r++){
        const float mn = fmaxf(m[r], tmax[r]);
        alpha[r] = __expf(m[r] - mn); m[r] = mn;
        c0[r] = __expf(c0[r] - mn);
        c1[r] = __expf(c1[r] - mn);
      }
      float rs[4];
#pragma unroll
      for (int r = 0; r < 4; r++) rs[r] = c0[r] + c1[r];
#pragma unroll
      for (int o = 1; o <= 8; o <<= 1)
#pragma unroll
        for (int r = 0; r < 4; r++) rs[r] += __shfl_xor(rs[r], o);
#pragma unroll
      for (int r = 0; r < 4; r++) lsum[r] = lsum[r] * alpha[r] + rs[r];
#pragma unroll
      for (int f = 0; f < 4; f++)
#pragma unroll
        for (int r = 0; r < 4; r++) oacc[f][r] *= alpha[r];
      // ---- P -> LDS (C-layout) then read back as A-frag ----
#pragma unroll
      for (int r = 0; r < 4; r++){
        Ps[w][quad * 4 + r][l16]      = f2bf(c0[r]);
        Ps[w][quad * 4 + r][16 + l16] = f2bf(c1[r]);
      }
      const short8 pa = ld8(&Ps[w][l16][quad * 8]);
      // ---- O += P V ----
#pragma unroll
      for (int f = 0; f < 4; f++){
        short8 vb = ld8(&Vt[f * 16 + l16][quad * 8]);
        oacc[f] = __builtin_amdgcn_mfma_f32_16x16x32_bf16(pa, vb, oacc[f], 0, 0, 0);
      }
    }
    __syncthreads();
  }
  // ---- epilogue: O/l, scatter (coalesced 64B per 16-lane group) ----
#pragma unroll
  for (int r = 0; r < 4; r++){
    const float inv = 1.f / lsum[r];
    const long row = base_bh + (long)(qw0 + quad * 4 + r) * strideT + l16;
#pragma unroll
    for (int f = 0; f < 4; f++) O[row + f * 16] = oacc[f][r] * inv;
  }
}

extern "C" void kernel_launch(void* const* d_in, const int* in_sizes, int n_in,
                              void* d_out, int out_size, void* d_ws, size_t ws_size,
                              hipStream_t stream){
  const float* x       = (const float*)d_in[0];
  const float* Wq      = (const float*)d_in[1];
  const float* Wk      = (const float*)d_in[2];
  const float* Wv      = (const float*)d_in[3];
  const float* gate_w  = (const float*)d_in[4];
  const float* gate_b  = (const float*)d_in[5];
  const float* p_w     = (const float*)d_in[6];
  const float* p_b     = (const float*)d_in[7];
  const float* out_w   = (const float*)d_in[8];
  const float* out_b   = (const float*)d_in[9];
  const float* clock_w = (const float*)d_in[10];
  const float* clock_b = (const float*)d_in[11];
  const float* ln1_g   = (const float*)d_in[12];
  const float* ln1_b   = (const float*)d_in[13];
  const float* ln2_g   = (const float*)d_in[14];
  const float* ln2_b   = (const float*)d_in[15];
  const float* mlp_w1  = (const float*)d_in[16];
  const float* mlp_b1  = (const float*)d_in[17];
  const float* mlp_w2  = (const float*)d_in[18];
  const float* mlp_b2  = (const float*)d_in[19];
  float* outp = (float*)d_out;   // reference output dtype is float32

  // workspace layout (floats); total ~25.43M floats ~= 97 MiB
  float* ws   = (float*)d_ws;
  float* XN   = ws;             // 4M  (xn; later H = LN2 out)
  float* Qb   = ws + 4194304;   // 4M
  float* Kb   = ws + 8388608;   // 4M
  float* Vb   = ws + 12582912;  // 4M
  float* Gb   = ws + 16777216;  // 4M  (gate raw -> gj; later O = attn out)
  float* Pb   = ws + 20971520;  // 4M  (p raw -> p_exp; later X1)
  float* CLKr = ws + 25165824;  // 64K (clock raw)
  float* cmax = ws + 25231360;  // 64K
  float* gsum = cmax + 65536;   // 64K (later psum)
  float* gpre = gsum + 65536;   // 64K (later ppre)
  float* pmax = gpre + 65536;   // 2K
  float* MID  = Qb;             // 16M, overlays dead Q/K/V/G at MLP time
  float* X1   = Pb;
  float* O    = Gb;
  float* H    = XN;

  ln_kernel<<<BT, 256, 0, stream>>>(x, ln1_g, ln1_b, XN);

  dim3 gD((DM + 63) / 64, BT / 64);
  gemm_kernel<0><<<gD, 256, 0, stream>>>(XN, Wq, nullptr, nullptr, Qb, BT, DM, DM);
  gemm_kernel<0><<<gD, 256, 0, stream>>>(XN, Wk, nullptr, nullptr, Kb, BT, DM, DM);
  gemm_kernel<0><<<gD, 256, 0, stream>>>(XN, Wv, nullptr, nullptr, Vb, BT, DM, DM);
  gemm_kernel<1><<<gD, 256, 0, stream>>>(XN, gate_w, gate_b, nullptr, Gb, BT, DM, DM);
  gemm_kernel<1><<<gD, 256, 0, stream>>>(XN, p_w, p_b, nullptr, Pb, BT, DM, DM);
  dim3 gC(1, BT / 64);
  gemm_kernel<1><<<gC, 256, 0, stream>>>(XN, clock_w, clock_b, nullptr, CLKr, BT, NH, DM);

  qkprep_kernel<<<16384, 256, 0, stream>>>(Qb, Kb);

  scan_p1<<<256, 256, 0, stream>>>(Gb, Pb, cmax, gsum);
  scan_p2<<<8, 256, 0, stream>>>(cmax, gsum, pmax, gpre);
  scan_p3<<<256, 256, 0, stream>>>(Gb, Pb, CLKr, Qb, Kb, pmax, gpre, gsum);
  scan_p4<<<8, 256, 0, stream>>>(gsum, gpre);
  scan_p5<<<256, 256, 0, stream>>>(Pb, Qb, Kb, gpre);

  dim3 gA(TSEQ / 64, 2 * NH);
  fattn_kernel<<<gA, 256, 0, stream>>>(Qb, Kb, Vb, O);

  gemm_kernel<2><<<gD, 256, 0, stream>>>(O, out_w, out_b, x, X1, BT, DM, DM);
  ln_kernel<<<BT, 256, 0, stream>>>(X1, ln2_g, ln2_b, H);
  dim3 gM1((4 * DM + 63) / 64, BT / 64);
  gemm_kernel<3><<<gM1, 256, 0, stream>>>(H, mlp_w1, mlp_b1, nullptr, MID, BT, 4 * DM, DM);
  gemm_kernel<4><<<gD, 256, 0, stream>>>(MID, mlp_w2, mlp_b2, X1, outp, BT, DM, 4 * DM);
}

// Round 6
// 928.389 us; speedup vs baseline: 9.8164x; 3.3729x over previous
//
#include <hip/hip_runtime.h>
#include <hip/hip_bf16.h>
#include <math.h>

typedef __hip_bfloat16 bf16;
typedef __attribute__((ext_vector_type(8))) short short8;
typedef __attribute__((ext_vector_type(4))) short short4v;
typedef __attribute__((ext_vector_type(4))) float f32x4;

#define BT   4096   // B*T rows
#define DM   1024
#define NH   16
#define DH   64
#define TSEQ 2048

__device__ __forceinline__ float wave_sum(float v){
#pragma unroll
  for (int o = 32; o; o >>= 1) v += __shfl_xor(v, o);
  return v;
}

__device__ __forceinline__ float block_sum(float v){
  __shared__ float sm[4];
  v = wave_sum(v);
  __syncthreads();
  if ((threadIdx.x & 63) == 0) sm[threadIdx.x >> 6] = v;
  __syncthreads();
  return sm[0] + sm[1] + sm[2] + sm[3];
}

__device__ __forceinline__ float softplusf(float x){
  return x > 20.f ? x : log1pf(expf(x));
}

__device__ __forceinline__ short f2bf(float f){
  unsigned u = __builtin_bit_cast(unsigned, f);
  u += 0x7FFF + ((u >> 16) & 1);          // RNE; inputs finite
  return (short)(u >> 16);
}

__device__ __forceinline__ short8 ld8(const short* p){
  short4v a = *(const short4v*)p;
  short4v b = *(const short4v*)(p + 4);
  short8 r;
  r[0]=a[0]; r[1]=a[1]; r[2]=a[2]; r[3]=a[3];
  r[4]=b[0]; r[5]=b[1]; r[6]=b[2]; r[7]=b[3];
  return r;
}

__device__ __forceinline__ void async16(const short* g, short* l){
  __builtin_amdgcn_global_load_lds(
      (const __attribute__((address_space(1))) void*)g,
      (__attribute__((address_space(3))) void*)l, 16, 0, 0);
}

// ---------------- weight convert+transpose: f32 [K][N] -> bf16 [N][K] ----------------
__global__ __launch_bounds__(256) void wt_kernel(const float* __restrict__ src,
    short* __restrict__ dst, int K, int N){
  __shared__ short T[32][33];
  const int tx = threadIdx.x & 31, ty = threadIdx.x >> 5;  // ty 0..7
  const int n0 = blockIdx.x << 5, k0 = blockIdx.y << 5;
#pragma unroll
  for (int r = 0; r < 4; r++){
    const int k = k0 + (ty << 2) + r;
    const int n = n0 + tx;
    T[tx][(ty << 2) + r] = (n < N) ? f2bf(src[(long)k * N + n]) : (short)0;
  }
  __syncthreads();
#pragma unroll
  for (int r = 0; r < 4; r++){
    const int n = n0 + (ty << 2) + r;
    if (n < N) dst[(long)n * K + k0 + tx] = T[(ty << 2) + r][tx];
  }
}

// ---------------- LayerNorm: one block per row of 1024, bf16 out ----------------
__global__ __launch_bounds__(256) void ln_kernel(const float* __restrict__ xin,
    const float* __restrict__ g, const float* __restrict__ bb, short* __restrict__ out){
  const long row = blockIdx.x;
  const int tid = threadIdx.x;
  float v[4];
#pragma unroll
  for (int i = 0; i < 4; i++) v[i] = xin[row * DM + tid + i * 256];
  float s = block_sum(v[0] + v[1] + v[2] + v[3]);
  const float mu = s * (1.f / DM);
  float d2 = 0.f;
#pragma unroll
  for (int i = 0; i < 4; i++){ float dd = v[i] - mu; d2 = fmaf(dd, dd, d2); }
  d2 = block_sum(d2);
  const float rstd = rsqrtf(d2 * (1.f / DM) + 1e-5f);
#pragma unroll
  for (int i = 0; i < 4; i++){
    int c = tid + i * 256;
    out[row * DM + c] = f2bf(fmaf((v[i] - mu) * rstd, g[c], bb[c]));
  }
}

// ---------------- MFMA GEMM: C[M,N] = A[M,K](bf16) @ Bt[N,K]^T(bf16) + epilogue ------
// EPI: 0 Cf=v | 1 Cf=v+bias | 2 Cf=v+bias+resf | 3 Cbf=bf16(gelu(v+bias))
// 128x128 tile, BK=32, 4 waves, 4x4 frags of mfma_f32_16x16x32_bf16 (m97 structure).
template <int EPI>
__global__ __launch_bounds__(256) void gemm_bt(
    const short* __restrict__ A, const short* __restrict__ Bt,
    const float* __restrict__ bias, const float* __restrict__ resf,
    float* __restrict__ Cf, short* __restrict__ Cbf, int M, int N, int K)
{
  __shared__ __attribute__((aligned(16))) short As[128 * 32];
  __shared__ __attribute__((aligned(16))) short Bs[128 * 32];
  const int tid = threadIdx.x;
  const int lane = tid & 63, w = tid >> 6;
  const int l16 = lane & 15, quad = lane >> 4;
  const int wm = w >> 1, wn = w & 1;
  const int bm0 = blockIdx.y << 7, bn0 = blockIdx.x << 7;

  f32x4 acc[4][4] = {};

  for (int k0 = 0; k0 < K; k0 += 32){
#pragma unroll
    for (int p = 0; p < 2; p++){
      const int lin = p * 256 + tid;        // 16B chunk index in tile
      const int r = lin >> 2, c = lin & 3;  // row 0..127, 16B chunk 0..3
      const short* ga = A + (long)(bm0 + r) * K + k0 + c * 8;
      const int rowB = min(bn0 + r, N - 1); // clamp for N<128 tiles (clock)
      const short* gb = Bt + (long)rowB * K + k0 + c * 8;
      async16(ga, &As[p * 2048 + (w << 9)]);
      async16(gb, &Bs[p * 2048 + (w << 9)]);
    }
    __syncthreads();
    short8 af[4], bfr[4];
#pragma unroll
    for (int i = 0; i < 4; i++){
      af[i]  = *(const short8*)&As[(wm * 64 + i * 16 + l16) * 32 + quad * 8];
      bfr[i] = *(const short8*)&Bs[(wn * 64 + i * 16 + l16) * 32 + quad * 8];
    }
#pragma unroll
    for (int i = 0; i < 4; i++)
#pragma unroll
      for (int j = 0; j < 4; j++)
        acc[i][j] = __builtin_amdgcn_mfma_f32_16x16x32_bf16(af[i], bfr[j], acc[i][j], 0, 0, 0);
    __syncthreads();
  }

#pragma unroll
  for (int i = 0; i < 4; i++){
#pragma unroll
    for (int r = 0; r < 4; r++){
      const int row = bm0 + wm * 64 + i * 16 + quad * 4 + r;
#pragma unroll
      for (int j = 0; j < 4; j++){
        const int col = bn0 + wn * 64 + j * 16 + l16;
        if (col < N){
          float v = acc[i][j][r];
          const long off = (long)row * N + col;
          if constexpr (EPI >= 1) v += bias[col];
          if constexpr (EPI == 2) v += resf[off];
          if constexpr (EPI == 3){
            v = 0.5f * v * (1.f + erff(v * 0.70710678118654752f));
            Cbf[off] = f2bf(v);
          } else {
            Cf[off] = v;
          }
        }
      }
    }
  }
}

// ---------------- l2norm + RoPE, one wave per (b,t,h) row of 64 ----------------
__global__ __launch_bounds__(256) void qkprep_kernel(float* __restrict__ Qb, float* __restrict__ Kb){
  const int lane = threadIdx.x & 63;
  const long row = ((long)blockIdx.x << 2) + (threadIdx.x >> 6);  // < B*T*H
  const int t = (int)((row >> 4) & (TSEQ - 1));
  const long base = (row << 6) + lane;
  const float freq = expf(-(float)(lane >> 1) * 0.28782313662425575f); // ln(1e4)/32
  const float th = (float)t * freq;
  const float sn = sinf(th), cn = cosf(th);
  {
    float q = Qb[base];
    float n = sqrtf(wave_sum(q * q));
    q = q / fmaxf(n, 1e-12f);
    float pr = __shfl_xor(q, 1);
    Qb[base] = (lane & 1) ? fmaf(pr, sn, q * cn) : fmaf(q, cn, -pr * sn);
  }
  {
    float k = Kb[base];
    float n = sqrtf(wave_sum(k * k));
    k = k / fmaxf(n, 1e-12f);
    float pr = __shfl_xor(k, 1);
    Kb[base] = (lane & 1) ? fmaf(pr, sn, k * cn) : fmaf(k, cn, -pr * sn);
  }
}

// ---------------- Chunked scans over T (32 chunks x 64) ----------------
__global__ __launch_bounds__(256) void scan_p1(float* __restrict__ G, const float* __restrict__ P,
    float* __restrict__ cmax, float* __restrict__ gsum){
  const int tid = blockIdx.x * 256 + threadIdx.x;    // 65536
  const int d = tid & 63, c = (tid >> 6) & 31, bh = tid >> 11;
  const int h = bh & 15, b = bh >> 4;
  const long base = (((long)(b * TSEQ + c * 64)) * NH + h) * 64 + d;
  float mx = -1e30f, gs = 0.f;
  for (int tt = 0; tt < 64; tt++){
    const long idx = base + (long)tt * (NH * 64);
    float gj = -softplusf(G[idx]);
    G[idx] = gj;
    gs += gj;
    mx = fmaxf(mx, P[idx]);
  }
  const int chain = bh * 64 + d;
  cmax[chain * 32 + c] = mx;
  gsum[chain * 32 + c] = gs;
}

__global__ void scan_p2(const float* __restrict__ cmax, const float* __restrict__ gsum,
                        float* __restrict__ pmax, float* __restrict__ gpre){
  const int chain = blockIdx.x * 256 + threadIdx.x;  // 2048
  float mx = -1e30f;
  for (int c = 0; c < 32; c++) mx = fmaxf(mx, cmax[chain * 32 + c]);
  pmax[chain] = mx;
  float run = 0.f;
  for (int c = 0; c < 32; c++){ gpre[chain * 32 + c] = run; run += gsum[chain * 32 + c]; }
}

__global__ __launch_bounds__(256) void scan_p3(const float* __restrict__ G, float* __restrict__ P,
    const float* __restrict__ CLKr, float* __restrict__ Q, float* __restrict__ K,
    const float* __restrict__ pmax, const float* __restrict__ gpre, float* __restrict__ psum){
  const int tid = blockIdx.x * 256 + threadIdx.x;
  const int d = tid & 63, c = (tid >> 6) & 31, bh = tid >> 11;
  const int h = bh & 15, b = bh >> 4;
  const int chain = bh * 64 + d;
  const long base = (((long)(b * TSEQ + c * 64)) * NH + h) * 64 + d;
  const float pm = pmax[chain];
  float grun = gpre[chain * 32 + c];
  float ps = 0.f;
  for (int tt = 0; tt < 64; tt++){
    const long idx = base + (long)tt * (NH * 64);
    const int t = c * 64 + tt;
    float clk = softplusf(CLKr[(long)(b * TSEQ + t) * NH + h]);
    float pe = expf(P[idx] - pm) * clk;
    P[idx] = pe; ps += pe;
    grun += G[idx];
    float gc = expf(fminf(fmaxf(grun, -60.f), 50.f));
    Q[idx] *= gc;
    K[idx] = K[idx] / (gc + 1e-8f);
  }
  psum[chain * 32 + c] = ps;
}

__global__ void scan_p4(const float* __restrict__ psum, float* __restrict__ ppre){
  const int chain = blockIdx.x * 256 + threadIdx.x;
  float run = 0.f;
  for (int c = 0; c < 32; c++){ ppre[chain * 32 + c] = run; run += psum[chain * 32 + c]; }
}

__global__ __launch_bounds__(256) void scan_p5(const float* __restrict__ P, float* __restrict__ Q,
    float* __restrict__ K, const float* __restrict__ ppre){
  const int tid = blockIdx.x * 256 + threadIdx.x;
  const int d = tid & 63, c = (tid >> 6) & 31, bh = tid >> 11;
  const int h = bh & 15, b = bh >> 4;
  const int chain = bh * 64 + d;
  const long base = (((long)(b * TSEQ + c * 64)) * NH + h) * 64 + d;
  float cs = ppre[chain * 32 + c];
  for (int tt = 0; tt < 64; tt++){
    const long idx = base + (long)tt * (NH * 64);
    float pe = P[idx];
    cs += pe;
    Q[idx] = Q[idx] / (cs + 1e-8f);
    K[idx] *= pe;
  }
}

// ---------------- MFMA flash attention (bf16 out) ----------------
__global__ __launch_bounds__(256) void fattn_kernel(const float* __restrict__ Q,
    const float* __restrict__ K, const float* __restrict__ V, short* __restrict__ O){
  __shared__ __attribute__((aligned(16))) short Ks[32][72];
  __shared__ __attribute__((aligned(16))) short Vt[64][36];
  __shared__ __attribute__((aligned(16))) short Ps[4][16][40];
  const int tid  = threadIdx.x;
  const int lane = tid & 63, w = tid >> 6;
  const int quad = lane >> 4, l16 = lane & 15;
  const int bh = blockIdx.y, h = bh & 15, b = bh >> 4;
  const int q0  = blockIdx.x << 6;
  const int qw0 = q0 + w * 16;
  const long strideT = NH * DH;
  const long base_bh = ((long)b * TSEQ * NH + h) * DH;

  short8 qa0, qa1;
  {
    const float* qp = Q + base_bh + (long)(qw0 + l16) * strideT + quad * 8;
#pragma unroll
    for (int j = 0; j < 8; j++) qa0[j] = f2bf(qp[j] * 0.125f);
#pragma unroll
    for (int j = 0; j < 8; j++) qa1[j] = f2bf(qp[32 + j] * 0.125f);
  }

  f32x4 oacc[4] = {{0,0,0,0},{0,0,0,0},{0,0,0,0},{0,0,0,0}};
  float m[4]    = {-1e30f,-1e30f,-1e30f,-1e30f};
  float lsum[4] = {0.f,0.f,0.f,0.f};

  const int ntiles = (q0 >> 5) + 2;
  const int kkey = tid >> 3;
  const int kd   = (tid & 7) << 3;

  for (int t = 0; t < ntiles; t++){
    const int kt0 = t << 5;
    {
      const long krow = base_bh + (long)(kt0 + kkey) * strideT + kd;
      const float* kp = K + krow;
      short8 kv;
#pragma unroll
      for (int j = 0; j < 8; j++) kv[j] = f2bf(kp[j]);
      *(short8*)&Ks[kkey][kd] = kv;
      const float* vp = V + krow;
#pragma unroll
      for (int j = 0; j < 8; j++) Vt[kd + j][kkey] = f2bf(vp[j]);
    }
    __syncthreads();
    if (kt0 <= qw0 + 15){
      f32x4 c0 = {0,0,0,0}, c1 = {0,0,0,0};
      {
        short8 kb00 = ld8(&Ks[l16][quad * 8]);
        short8 kb01 = ld8(&Ks[l16][32 + quad * 8]);
        short8 kb10 = ld8(&Ks[16 + l16][quad * 8]);
        short8 kb11 = ld8(&Ks[16 + l16][32 + quad * 8]);
        c0 = __builtin_amdgcn_mfma_f32_16x16x32_bf16(qa0, kb00, c0, 0, 0, 0);
        c0 = __builtin_amdgcn_mfma_f32_16x16x32_bf16(qa1, kb01, c0, 0, 0, 0);
        c1 = __builtin_amdgcn_mfma_f32_16x16x32_bf16(qa0, kb10, c1, 0, 0, 0);
        c1 = __builtin_amdgcn_mfma_f32_16x16x32_bf16(qa1, kb11, c1, 0, 0, 0);
      }
      if (kt0 + 31 > qw0){
#pragma unroll
        for (int r = 0; r < 4; r++){
          const int q = qw0 + quad * 4 + r;
          if (kt0 + l16 > q)      c0[r] = -1e30f;
          if (kt0 + 16 + l16 > q) c1[r] = -1e30f;
        }
      }
      float tmax[4], alpha[4];
#pragma unroll
      for (int r = 0; r < 4; r++) tmax[r] = fmaxf(c0[r], c1[r]);
#pragma unroll
      for (int o = 1; o <= 8; o <<= 1)
#pragma unroll
        for (int r = 0; r < 4; r++) tmax[r] = fmaxf(tmax[r], __shfl_xor(tmax[r], o));
#pragma unroll
      for (int r = 0; r < 4; r++){
        const float mn = fmaxf(m[r], tmax[r]);
        alpha[r] = __expf(m[r] - mn); m[r] = mn;
        c0[r] = __expf(c0[r] - mn);
        c1[r] = __expf(c1[r] - mn);
      }
      float rs[4];
#pragma unroll
      for (int r = 0; r < 4; r++) rs[r] = c0[r] + c1[r];
#pragma unroll
      for (int o = 1; o <= 8; o <<= 1)
#pragma unroll
        for (int r = 0; r < 4; r++) rs[r] += __shfl_xor(rs[r], o);
#pragma unroll
      for (int r = 0; r < 4; r++) lsum[r] = lsum[r] * alpha[r] + rs[r];
#pragma unroll
      for (int f = 0; f < 4; f++)
#pragma unroll
        for (int r = 0; r < 4; r++) oacc[f][r] *= alpha[r];
#pragma unroll
      for (int r = 0; r < 4; r++){
        Ps[w][quad * 4 + r][l16]      = f2bf(c0[r]);
        Ps[w][quad * 4 + r][16 + l16] = f2bf(c1[r]);
      }
      const short8 pa = ld8(&Ps[w][l16][quad * 8]);
#pragma unroll
      for (int f = 0; f < 4; f++){
        short8 vb = ld8(&Vt[f * 16 + l16][quad * 8]);
        oacc[f] = __builtin_amdgcn_mfma_f32_16x16x32_bf16(pa, vb, oacc[f], 0, 0, 0);
      }
    }
    __syncthreads();
  }
#pragma unroll
  for (int r = 0; r < 4; r++){
    const float inv = 1.f / lsum[r];
    const long row = base_bh + (long)(qw0 + quad * 4 + r) * strideT + l16;
#pragma unroll
    for (int f = 0; f < 4; f++) O[row + f * 16] = f2bf(oacc[f][r] * inv);
  }
}

extern "C" void kernel_launch(void* const* d_in, const int* in_sizes, int n_in,
                              void* d_out, int out_size, void* d_ws, size_t ws_size,
                              hipStream_t stream){
  const float* x       = (const float*)d_in[0];
  const float* Wq      = (const float*)d_in[1];
  const float* Wk      = (const float*)d_in[2];
  const float* Wv      = (const float*)d_in[3];
  const float* gate_w  = (const float*)d_in[4];
  const float* gate_b  = (const float*)d_in[5];
  const float* p_w     = (const float*)d_in[6];
  const float* p_b     = (const float*)d_in[7];
  const float* out_w   = (const float*)d_in[8];
  const float* out_b   = (const float*)d_in[9];
  const float* clock_w = (const float*)d_in[10];
  const float* clock_b = (const float*)d_in[11];
  const float* ln1_g   = (const float*)d_in[12];
  const float* ln1_b   = (const float*)d_in[13];
  const float* ln2_g   = (const float*)d_in[14];
  const float* ln2_b   = (const float*)d_in[15];
  const float* mlp_w1  = (const float*)d_in[16];
  const float* mlp_b1  = (const float*)d_in[17];
  const float* mlp_w2  = (const float*)d_in[18];
  const float* mlp_b2  = (const float*)d_in[19];
  float* outp = (float*)d_out;

  // ---- workspace layout (~117 MB) ----
  float* ws   = (float*)d_ws;
  float* Qb   = ws;                     // 4M f32
  float* Kb   = ws + 4194304;           // 4M f32
  float* Vb   = ws + 8388608;           // 4M f32
  float* Gb   = ws + 12582912;          // 4M f32 (gj)
  float* Pb   = ws + 16777216;          // 4M f32 (p_exp; later X1)
  float* CLKr = ws + 20971520;          // 64K
  float* cmax = ws + 21037056;          // 64K
  float* gsum = ws + 21102592;          // 64K (psum)
  float* gpre = ws + 21168128;          // 64K (ppre)
  float* pmax = ws + 21233664;          // 2K
  short* sb   = (short*)(ws + 21235712);
  short* XNb  = sb;                     // 4M bf16 (LN1 out)
  short* WqT  = sb + 4194304;           // 1M bf16 each
  short* WkT  = WqT + 1048576;
  short* WvT  = WkT + 1048576;
  short* GwT  = WvT + 1048576;
  short* PwT  = GwT + 1048576;
  short* OwT  = PwT + 1048576;
  short* W1T  = OwT + 1048576;          // 4M bf16 [4096][1024]
  short* W2T  = W1T + 4194304;          // 4M bf16 [1024][4096]
  short* CwT  = W2T + 4194304;          // 16K bf16 [16][1024]
  // overlays (regions dead by the time these are written):
  short* MID = (short*)ws;              // 16M bf16 over Qb+Kb
  short* Hb  = (short*)(ws + 8388608);  // 4M bf16 over Vb
  short* Ob  = (short*)(ws + 12582912); // 4M bf16 over Gb
  float* X1  = Pb;

  // ---- weight convert+transpose (bf16, [N][K]) ----
  wt_kernel<<<dim3(32, 32), 256, 0, stream>>>(Wq, WqT, DM, DM);
  wt_kernel<<<dim3(32, 32), 256, 0, stream>>>(Wk, WkT, DM, DM);
  wt_kernel<<<dim3(32, 32), 256, 0, stream>>>(Wv, WvT, DM, DM);
  wt_kernel<<<dim3(32, 32), 256, 0, stream>>>(gate_w, GwT, DM, DM);
  wt_kernel<<<dim3(32, 32), 256, 0, stream>>>(p_w, PwT, DM, DM);
  wt_kernel<<<dim3(32, 32), 256, 0, stream>>>(out_w, OwT, DM, DM);
  wt_kernel<<<dim3(128, 32), 256, 0, stream>>>(mlp_w1, W1T, DM, 4 * DM);
  wt_kernel<<<dim3(32, 128), 256, 0, stream>>>(mlp_w2, W2T, 4 * DM, DM);
  wt_kernel<<<dim3(1, 32), 256, 0, stream>>>(clock_w, CwT, DM, NH);

  ln_kernel<<<BT, 256, 0, stream>>>(x, ln1_g, ln1_b, XNb);

  dim3 gP(DM / 128, BT / 128);          // (8, 32)
  gemm_bt<0><<<gP, 256, 0, stream>>>(XNb, WqT, nullptr, nullptr, Qb, nullptr, BT, DM, DM);
  gemm_bt<0><<<gP, 256, 0, stream>>>(XNb, WkT, nullptr, nullptr, Kb, nullptr, BT, DM, DM);
  gemm_bt<0><<<gP, 256, 0, stream>>>(XNb, WvT, nullptr, nullptr, Vb, nullptr, BT, DM, DM);
  gemm_bt<1><<<gP, 256, 0, stream>>>(XNb, GwT, gate_b, nullptr, Gb, nullptr, BT, DM, DM);
  gemm_bt<1><<<gP, 256, 0, stream>>>(XNb, PwT, p_b, nullptr, Pb, nullptr, BT, DM, DM);
  gemm_bt<1><<<dim3(1, BT / 128), 256, 0, stream>>>(XNb, CwT, clock_b, nullptr, CLKr, nullptr, BT, NH, DM);

  qkprep_kernel<<<16384, 256, 0, stream>>>(Qb, Kb);

  scan_p1<<<256, 256, 0, stream>>>(Gb, Pb, cmax, gsum);
  scan_p2<<<8, 256, 0, stream>>>(cmax, gsum, pmax, gpre);
  scan_p3<<<256, 256, 0, stream>>>(Gb, Pb, CLKr, Qb, Kb, pmax, gpre, gsum);
  scan_p4<<<8, 256, 0, stream>>>(gsum, gpre);
  scan_p5<<<256, 256, 0, stream>>>(Pb, Qb, Kb, gpre);

  dim3 gA(TSEQ / 64, 2 * NH);
  fattn_kernel<<<gA, 256, 0, stream>>>(Qb, Kb, Vb, Ob);

  gemm_bt<2><<<gP, 256, 0, stream>>>(Ob, OwT, out_b, x, X1, nullptr, BT, DM, DM);
  ln_kernel<<<BT, 256, 0, stream>>>(X1, ln2_g, ln2_b, Hb);
  dim3 gM1(4 * DM / 128, BT / 128);     // (32, 32)
  gemm_bt<3><<<gM1, 256, 0, stream>>>(Hb, W1T, mlp_b1, nullptr, nullptr, MID, BT, 4 * DM, DM);
  gemm_bt<2><<<gP, 256, 0, stream>>>(MID, W2T, mlp_b2, X1, outp, nullptr, BT, DM, 4 * DM);
}

// Round 8
// 785.753 us; speedup vs baseline: 11.5983x; 1.1815x over previous
//
#include <hip/hip_runtime.h>
#include <hip/hip_bf16.h>
#include <math.h>

typedef __hip_bfloat16 bf16;
typedef __attribute__((ext_vector_type(8))) short short8;
typedef __attribute__((ext_vector_type(4))) short short4v;
typedef __attribute__((ext_vector_type(4))) float f32x4;

#define BT   4096   // B*T rows
#define DM   1024
#define NH   16
#define DH   64
#define TSEQ 2048

__device__ __forceinline__ float wave_sum(float v){
#pragma unroll
  for (int o = 32; o; o >>= 1) v += __shfl_xor(v, o);
  return v;
}

__device__ __forceinline__ float block_sum(float v){
  __shared__ float sm[4];
  v = wave_sum(v);
  __syncthreads();
  if ((threadIdx.x & 63) == 0) sm[threadIdx.x >> 6] = v;
  __syncthreads();
  return sm[0] + sm[1] + sm[2] + sm[3];
}

__device__ __forceinline__ float softplusf(float x){
  return x > 20.f ? x : log1pf(expf(x));
}

__device__ __forceinline__ short f2bf(float f){
  unsigned u = __builtin_bit_cast(unsigned, f);
  u += 0x7FFF + ((u >> 16) & 1);          // RNE; inputs finite
  return (short)(u >> 16);
}

__device__ __forceinline__ short8 ld8(const short* p){  // two 8B LDS reads
  short4v a = *(const short4v*)p;
  short4v b = *(const short4v*)(p + 4);
  short8 r;
  r[0]=a[0]; r[1]=a[1]; r[2]=a[2]; r[3]=a[3];
  r[4]=b[0]; r[5]=b[1]; r[6]=b[2]; r[7]=b[3];
  return r;
}

__device__ __forceinline__ void async16(const short* g, short* l){
  __builtin_amdgcn_global_load_lds(
      (const __attribute__((address_space(1))) void*)g,
      (__attribute__((address_space(3))) void*)l, 16, 0, 0);
}

// ---------------- weight convert+transpose: f32 [K][N] -> bf16 [N][K] ----------------
__global__ __launch_bounds__(256) void wt_kernel(const float* __restrict__ src,
    short* __restrict__ dst, int K, int N){
  __shared__ short T[32][33];
  const int tx = threadIdx.x & 31, ty = threadIdx.x >> 5;  // ty 0..7
  const int n0 = blockIdx.x << 5, k0 = blockIdx.y << 5;
#pragma unroll
  for (int r = 0; r < 4; r++){
    const int k = k0 + (ty << 2) + r;
    const int n = n0 + tx;
    T[tx][(ty << 2) + r] = (n < N) ? f2bf(src[(long)k * N + n]) : (short)0;
  }
  __syncthreads();
#pragma unroll
  for (int r = 0; r < 4; r++){
    const int n = n0 + (ty << 2) + r;
    if (n < N) dst[(long)n * K + k0 + tx] = T[(ty << 2) + r][tx];
  }
}

// ---------------- bias concat fill: [0..3071]=0, gate_b, p_b ----------------
__global__ __launch_bounds__(256) void biascat_fill(const float* __restrict__ gb,
    const float* __restrict__ pb, float* __restrict__ out){
  const int i = blockIdx.x * 256 + threadIdx.x;   // 5120
  if (i >= 5 * DM) return;
  float v = 0.f;
  if (i >= 4096) v = pb[i - 4096];
  else if (i >= 3072) v = gb[i - 3072];
  out[i] = v;
}

// ---------------- LayerNorm: one block per row of 1024, bf16 out ----------------
__global__ __launch_bounds__(256) void ln_kernel(const float* __restrict__ xin,
    const float* __restrict__ g, const float* __restrict__ bb, short* __restrict__ out){
  const long row = blockIdx.x;
  const int tid = threadIdx.x;
  float v[4];
#pragma unroll
  for (int i = 0; i < 4; i++) v[i] = xin[row * DM + tid + i * 256];
  float s = block_sum(v[0] + v[1] + v[2] + v[3]);
  const float mu = s * (1.f / DM);
  float d2 = 0.f;
#pragma unroll
  for (int i = 0; i < 4; i++){ float dd = v[i] - mu; d2 = fmaf(dd, dd, d2); }
  d2 = block_sum(d2);
  const float rstd = rsqrtf(d2 * (1.f / DM) + 1e-5f);
#pragma unroll
  for (int i = 0; i < 4; i++){
    int c = tid + i * 256;
    out[row * DM + c] = f2bf(fmaf((v[i] - mu) * rstd, g[c], bb[c]));
  }
}

// ---------------- MFMA GEMM: C[M,N] = A[M,K](bf16) @ Bt[N,K]^T(bf16) + epilogue ------
// EPI: 0 Cf=v | 1 Cf=v+bias | 2 Cf=v+bias+resf | 3 Cbf=bf16(gelu(v+bias))
//      5 proj-scatter: v+=bias; Cf[(col>>10)*4194304 + row*1024 + (col&1023)] = v
template <int EPI>
__global__ __launch_bounds__(256) void gemm_bt(
    const short* __restrict__ A, const short* __restrict__ Bt,
    const float* __restrict__ bias, const float* __restrict__ resf,
    float* __restrict__ Cf, short* __restrict__ Cbf, int M, int N, int K)
{
  __shared__ __attribute__((aligned(16))) short As[128 * 32];
  __shared__ __attribute__((aligned(16))) short Bs[128 * 32];
  const int tid = threadIdx.x;
  const int lane = tid & 63, w = tid >> 6;
  const int l16 = lane & 15, quad = lane >> 4;
  const int wm = w >> 1, wn = w & 1;
  const int bm0 = blockIdx.y << 7, bn0 = blockIdx.x << 7;

  f32x4 acc[4][4] = {};

  for (int k0 = 0; k0 < K; k0 += 32){
#pragma unroll
    for (int p = 0; p < 2; p++){
      const int lin = p * 256 + tid;        // 16B chunk index in tile
      const int r = lin >> 2, c = lin & 3;  // row 0..127, 16B chunk 0..3
      const short* ga = A + (long)(bm0 + r) * K + k0 + c * 8;
      const int rowB = min(bn0 + r, N - 1); // clamp for N<128 tiles (clock)
      const short* gb = Bt + (long)rowB * K + k0 + c * 8;
      async16(ga, &As[p * 2048 + (w << 9)]);
      async16(gb, &Bs[p * 2048 + (w << 9)]);
    }
    __syncthreads();
    short8 af[4], bfr[4];
#pragma unroll
    for (int i = 0; i < 4; i++){
      af[i]  = *(const short8*)&As[(wm * 64 + i * 16 + l16) * 32 + quad * 8];
      bfr[i] = *(const short8*)&Bs[(wn * 64 + i * 16 + l16) * 32 + quad * 8];
    }
#pragma unroll
    for (int i = 0; i < 4; i++)
#pragma unroll
      for (int j = 0; j < 4; j++)
        acc[i][j] = __builtin_amdgcn_mfma_f32_16x16x32_bf16(af[i], bfr[j], acc[i][j], 0, 0, 0);
    __syncthreads();
  }

#pragma unroll
  for (int i = 0; i < 4; i++){
#pragma unroll
    for (int r = 0; r < 4; r++){
      const int row = bm0 + wm * 64 + i * 16 + quad * 4 + r;
#pragma unroll
      for (int j = 0; j < 4; j++){
        const int col = bn0 + wn * 64 + j * 16 + l16;
        if (col < N){
          float v = acc[i][j][r];
          const long off = (long)row * N + col;
          if constexpr (EPI >= 1) v += bias[col];
          if constexpr (EPI == 2) v += resf[off];
          if constexpr (EPI == 3){
            v = 0.5f * v * (1.f + erff(v * 0.70710678118654752f));
            Cbf[off] = f2bf(v);
          } else if constexpr (EPI == 5){
            Cf[(long)(col >> 10) * 4194304 + (long)row * 1024 + (col & 1023)] = v;
          } else {
            Cf[off] = v;
          }
        }
      }
    }
  }
}

// ------- l2norm + RoPE on Q,K (in-place f32) + V f32->bf16; one wave per (b,t,h) -------
__global__ __launch_bounds__(256) void qkprep_kernel(float* __restrict__ Qb, float* __restrict__ Kb,
    const float* __restrict__ Vb, short* __restrict__ Vh){
  const int lane = threadIdx.x & 63;
  const long row = ((long)blockIdx.x << 2) + (threadIdx.x >> 6);  // < B*T*H
  const int t = (int)((row >> 4) & (TSEQ - 1));
  const long base = (row << 6) + lane;
  const float freq = expf(-(float)(lane >> 1) * 0.28782313662425575f); // ln(1e4)/32
  const float th = (float)t * freq;
  const float sn = sinf(th), cn = cosf(th);
  {
    float q = Qb[base];
    float n = sqrtf(wave_sum(q * q));
    q = q / fmaxf(n, 1e-12f);
    float pr = __shfl_xor(q, 1);
    Qb[base] = (lane & 1) ? fmaf(pr, sn, q * cn) : fmaf(q, cn, -pr * sn);
  }
  {
    float k = Kb[base];
    float n = sqrtf(wave_sum(k * k));
    k = k / fmaxf(n, 1e-12f);
    float pr = __shfl_xor(k, 1);
    Kb[base] = (lane & 1) ? fmaf(pr, sn, k * cn) : fmaf(k, cn, -pr * sn);
  }
  Vh[base] = f2bf(Vb[base]);
}

// ---------------- Chunked scans over T (32 chunks x 64) ----------------
__global__ __launch_bounds__(256) void scan_p1(float* __restrict__ G, const float* __restrict__ P,
    float* __restrict__ cmax, float* __restrict__ gsum){
  const int tid = blockIdx.x * 256 + threadIdx.x;    // 65536
  const int d = tid & 63, c = (tid >> 6) & 31, bh = tid >> 11;
  const int h = bh & 15, b = bh >> 4;
  const long base = (((long)(b * TSEQ + c * 64)) * NH + h) * 64 + d;
  float mx = -1e30f, gs = 0.f;
  for (int tt = 0; tt < 64; tt++){
    const long idx = base + (long)tt * (NH * 64);
    float gj = -softplusf(G[idx]);
    G[idx] = gj;
    gs += gj;
    mx = fmaxf(mx, P[idx]);
  }
  const int chain = bh * 64 + d;
  cmax[chain * 32 + c] = mx;
  gsum[chain * 32 + c] = gs;
}

__global__ void scan_p2(const float* __restrict__ cmax, const float* __restrict__ gsum,
                        float* __restrict__ pmax, float* __restrict__ gpre){
  const int chain = blockIdx.x * 256 + threadIdx.x;  // 2048
  float mx = -1e30f;
  for (int c = 0; c < 32; c++) mx = fmaxf(mx, cmax[chain * 32 + c]);
  pmax[chain] = mx;
  float run = 0.f;
  for (int c = 0; c < 32; c++){ gpre[chain * 32 + c] = run; run += gsum[chain * 32 + c]; }
}

__global__ __launch_bounds__(256) void scan_p3(const float* __restrict__ G, float* __restrict__ P,
    const float* __restrict__ CLKr, float* __restrict__ Q, float* __restrict__ K,
    const float* __restrict__ pmax, const float* __restrict__ gpre, float* __restrict__ psum){
  const int tid = blockIdx.x * 256 + threadIdx.x;
  const int d = tid & 63, c = (tid >> 6) & 31, bh = tid >> 11;
  const int h = bh & 15, b = bh >> 4;
  const int chain = bh * 64 + d;
  const long base = (((long)(b * TSEQ + c * 64)) * NH + h) * 64 + d;
  const float pm = pmax[chain];
  float grun = gpre[chain * 32 + c];
  float ps = 0.f;
  for (int tt = 0; tt < 64; tt++){
    const long idx = base + (long)tt * (NH * 64);
    const int t = c * 64 + tt;
    float clk = softplusf(CLKr[(long)(b * TSEQ + t) * NH + h]);
    float pe = expf(P[idx] - pm) * clk;
    P[idx] = pe; ps += pe;
    grun += G[idx];
    float gc = expf(fminf(fmaxf(grun, -60.f), 50.f));
    Q[idx] *= gc;
    K[idx] = K[idx] / (gc + 1e-8f);
  }
  psum[chain * 32 + c] = ps;
}

__global__ void scan_p4(const float* __restrict__ psum, float* __restrict__ ppre){
  const int chain = blockIdx.x * 256 + threadIdx.x;
  float run = 0.f;
  for (int c = 0; c < 32; c++){ ppre[chain * 32 + c] = run; run += psum[chain * 32 + c]; }
}

// final scan: emits bf16 Qh (pre-scaled by 0.125) and bf16 Kh
__global__ __launch_bounds__(256) void scan_p5(const float* __restrict__ P, const float* __restrict__ Q,
    const float* __restrict__ K, const float* __restrict__ ppre,
    short* __restrict__ Qh, short* __restrict__ Kh){
  const int tid = blockIdx.x * 256 + threadIdx.x;
  const int d = tid & 63, c = (tid >> 6) & 31, bh = tid >> 11;
  const int h = bh & 15, b = bh >> 4;
  const int chain = bh * 64 + d;
  const long base = (((long)(b * TSEQ + c * 64)) * NH + h) * 64 + d;
  float cs = ppre[chain * 32 + c];
  for (int tt = 0; tt < 64; tt++){
    const long idx = base + (long)tt * (NH * 64);
    float pe = P[idx];
    cs += pe;
    Qh[idx] = f2bf(Q[idx] / (cs + 1e-8f) * 0.125f);
    Kh[idx] = f2bf(K[idx] * pe);
  }
}

// ---------------- MFMA flash attention, 64-key tiles, bf16 in/out ----------------
__global__ __launch_bounds__(256) void fattn_kernel(const short* __restrict__ Qh,
    const short* __restrict__ Kh, const short* __restrict__ Vh, short* __restrict__ O){
  __shared__ __attribute__((aligned(16))) short Ks[64][72];   // [key][d]
  __shared__ __attribute__((aligned(16))) short Vt[64][68];   // [d][key]
  __shared__ __attribute__((aligned(16))) short Ps[4][16][72];
  const int tid  = threadIdx.x;
  const int lane = tid & 63, w = tid >> 6;
  const int quad = lane >> 4, l16 = lane & 15;
  const int bh = blockIdx.y, h = bh & 15, b = bh >> 4;
  const int qt = (int)(gridDim.x - 1 - blockIdx.x);   // heavy blocks first
  const int q0  = qt << 6;
  const int qw0 = q0 + w * 16;
  const long strideT = NH * DH;
  const long base_bh = ((long)b * TSEQ * NH + h) * DH;

  // Q fragments (bf16, pre-scaled)
  const short* qp = Qh + base_bh + (long)(qw0 + l16) * strideT + quad * 8;
  const short8 qa0 = *(const short8*)qp;
  const short8 qa1 = *(const short8*)(qp + 32);

  f32x4 oacc[4] = {{0,0,0,0},{0,0,0,0},{0,0,0,0},{0,0,0,0}};
  float m[4]    = {-1e30f,-1e30f,-1e30f,-1e30f};
  float lsum[4] = {0.f,0.f,0.f,0.f};

  // staging assignments
  const int krow = tid >> 2, kcol = (tid & 3) << 4;  // K: 64 rows x 64 shorts
  const int vkey = tid & 63, vd0 = (tid >> 6) << 4;  // V: transpose, 16 d per thread

  const int ntiles = qt + 1;
  for (int t = 0; t < ntiles; t++){
    const int kt0 = t << 6;
    {
      const short* ks = Kh + base_bh + (long)(kt0 + krow) * strideT + kcol;
      *(short8*)&Ks[krow][kcol]     = *(const short8*)ks;
      *(short8*)&Ks[krow][kcol + 8] = *(const short8*)(ks + 8);
      const short* vs = Vh + base_bh + (long)(kt0 + vkey) * strideT + vd0;
      const short8 v0 = *(const short8*)vs;
      const short8 v1 = *(const short8*)(vs + 8);
#pragma unroll
      for (int j = 0; j < 8; j++) Vt[vd0 + j][vkey] = v0[j];
#pragma unroll
      for (int j = 0; j < 8; j++) Vt[vd0 + 8 + j][vkey] = v1[j];
    }
    __syncthreads();
    // ---- S = Q K^T : 4 key-groups of 16 ----
    f32x4 c[4] = {{0,0,0,0},{0,0,0,0},{0,0,0,0},{0,0,0,0}};
#pragma unroll
    for (int kg = 0; kg < 4; kg++){
      const short8 b0 = ld8(&Ks[kg * 16 + l16][quad * 8]);
      const short8 b1 = ld8(&Ks[kg * 16 + l16][32 + quad * 8]);
      c[kg] = __builtin_amdgcn_mfma_f32_16x16x32_bf16(qa0, b0, c[kg], 0, 0, 0);
      c[kg] = __builtin_amdgcn_mfma_f32_16x16x32_bf16(qa1, b1, c[kg], 0, 0, 0);
    }
    // ---- causal mask ----
    if (kt0 + 63 > qw0){
#pragma unroll
      for (int kg = 0; kg < 4; kg++)
#pragma unroll
        for (int r = 0; r < 4; r++){
          const int qq = qw0 + quad * 4 + r;
          if (kt0 + kg * 16 + l16 > qq) c[kg][r] = -1e30f;
        }
    }
    // ---- online softmax ----
    float tmax[4], alpha[4];
#pragma unroll
    for (int r = 0; r < 4; r++)
      tmax[r] = fmaxf(fmaxf(c[0][r], c[1][r]), fmaxf(c[2][r], c[3][r]));
#pragma unroll
    for (int o = 1; o <= 8; o <<= 1)
#pragma unroll
      for (int r = 0; r < 4; r++) tmax[r] = fmaxf(tmax[r], __shfl_xor(tmax[r], o));
#pragma unroll
    for (int r = 0; r < 4; r++){
      const float mn = fmaxf(m[r], tmax[r]);
      alpha[r] = __expf(m[r] - mn); m[r] = mn;
#pragma unroll
      for (int kg = 0; kg < 4; kg++) c[kg][r] = __expf(c[kg][r] - mn);
    }
    float rs[4];
#pragma unroll
    for (int r = 0; r < 4; r++) rs[r] = (c[0][r] + c[1][r]) + (c[2][r] + c[3][r]);
#pragma unroll
    for (int o = 1; o <= 8; o <<= 1)
#pragma unroll
      for (int r = 0; r < 4; r++) rs[r] += __shfl_xor(rs[r], o);
#pragma unroll
    for (int r = 0; r < 4; r++) lsum[r] = lsum[r] * alpha[r] + rs[r];
#pragma unroll
    for (int f = 0; f < 4; f++)
#pragma unroll
      for (int r = 0; r < 4; r++) oacc[f][r] *= alpha[r];
    // ---- P -> LDS (C-layout) -> A-frags ----
#pragma unroll
    for (int kg = 0; kg < 4; kg++)
#pragma unroll
      for (int r = 0; r < 4; r++)
        Ps[w][quad * 4 + r][kg * 16 + l16] = f2bf(c[kg][r]);
    const short8 pa0 = ld8(&Ps[w][l16][quad * 8]);
    const short8 pa1 = ld8(&Ps[w][l16][32 + quad * 8]);
    // ---- O += P V ----
#pragma unroll
    for (int f = 0; f < 4; f++){
      const short8 vb0 = ld8(&Vt[f * 16 + l16][quad * 8]);
      const short8 vb1 = ld8(&Vt[f * 16 + l16][32 + quad * 8]);
      oacc[f] = __builtin_amdgcn_mfma_f32_16x16x32_bf16(pa0, vb0, oacc[f], 0, 0, 0);
      oacc[f] = __builtin_amdgcn_mfma_f32_16x16x32_bf16(pa1, vb1, oacc[f], 0, 0, 0);
    }
    __syncthreads();
  }
  // ---- epilogue ----
#pragma unroll
  for (int r = 0; r < 4; r++){
    const float inv = 1.f / lsum[r];
    const long row = base_bh + (long)(qw0 + quad * 4 + r) * strideT + l16;
#pragma unroll
    for (int f = 0; f < 4; f++) O[row + f * 16] = f2bf(oacc[f][r] * inv);
  }
}

extern "C" void kernel_launch(void* const* d_in, const int* in_sizes, int n_in,
                              void* d_out, int out_size, void* d_ws, size_t ws_size,
                              hipStream_t stream){
  const float* x       = (const float*)d_in[0];
  const float* Wq      = (const float*)d_in[1];
  const float* Wk      = (const float*)d_in[2];
  const float* Wv      = (const float*)d_in[3];
  const float* gate_w  = (const float*)d_in[4];
  const float* gate_b  = (const float*)d_in[5];
  const float* p_w     = (const float*)d_in[6];
  const float* p_b     = (const float*)d_in[7];
  const float* out_w   = (const float*)d_in[8];
  const float* out_b   = (const float*)d_in[9];
  const float* clock_w = (const float*)d_in[10];
  const float* clock_b = (const float*)d_in[11];
  const float* ln1_g   = (const float*)d_in[12];
  const float* ln1_b   = (const float*)d_in[13];
  const float* ln2_g   = (const float*)d_in[14];
  const float* ln2_b   = (const float*)d_in[15];
  const float* mlp_w1  = (const float*)d_in[16];
  const float* mlp_b1  = (const float*)d_in[17];
  const float* mlp_w2  = (const float*)d_in[18];
  const float* mlp_b2  = (const float*)d_in[19];
  float* outp = (float*)d_out;

  // ---- workspace layout (exactly round-6 footprint: 122,724,352 B) ----
  float* ws   = (float*)d_ws;
  float* C5   = ws;                     // 20M f32: Qb,Kb,Vb,Gb,Pb contiguous
  float* Qb   = ws;
  float* Kb   = ws + 4194304;
  float* Vb   = ws + 8388608;
  float* Gb   = ws + 12582912;
  float* Pb   = ws + 16777216;          // later X1
  // small buffers AFTER the f32 block (disjoint from Pb!):
  float* CLKr = ws + 20971520;          // 64K
  float* cmax = CLKr + 65536;           // 64K
  float* gsum = cmax + 65536;           // 64K (psum)
  float* gpre = gsum + 65536;           // 64K (ppre)
  float* pmax = gpre + 65536;           // 2K
  float* biascat = cmax;                // shares cmax: biascat read (proj GEMM) finishes
                                        // before scan_p1 first writes cmax
  short* sb   = (short*)(ws + 21235712);
  short* XNb  = sb;                     // 4M shorts (LN1 out); later Vh overlay
  short* Vh   = sb;                     //   (V bf16, written after XNb dead)
  short* WcT  = sb + 4194304;           // 5M shorts: concat [5120][1024]
  short* OwT  = WcT + 5242880;          // 1M
  short* W1T  = OwT + 1048576;          // 4M [4096][1024]
  short* W2T  = W1T + 4194304;          // 4M [1024][4096]
  short* CwT  = W2T + 4194304;          // 16K [16][1024]
  // overlays (regions dead by the time these are written):
  short* Qh  = (short*)(ws + 8388608);            // over dead Vb (f32)
  short* Kh  = (short*)(ws + 8388608 + 2097152);
  short* MID = (short*)ws;                        // 16M shorts over Qb+Kb
  short* Ob  = (short*)(ws + 12582912);           // over dead Gb (first half)
  short* Hb  = (short*)(ws + 12582912 + 2097152); // over dead Gb (second half)
  float* X1  = Pb;

  // ---- weight convert+transpose (bf16, [N][K]) ----
  wt_kernel<<<dim3(32, 32), 256, 0, stream>>>(Wq,     WcT,               DM, DM);
  wt_kernel<<<dim3(32, 32), 256, 0, stream>>>(Wk,     WcT + 1048576,     DM, DM);
  wt_kernel<<<dim3(32, 32), 256, 0, stream>>>(Wv,     WcT + 2097152,     DM, DM);
  wt_kernel<<<dim3(32, 32), 256, 0, stream>>>(gate_w, WcT + 3145728,     DM, DM);
  wt_kernel<<<dim3(32, 32), 256, 0, stream>>>(p_w,    WcT + 4194304,     DM, DM);
  wt_kernel<<<dim3(32, 32), 256, 0, stream>>>(out_w,  OwT,               DM, DM);
  wt_kernel<<<dim3(128, 32), 256, 0, stream>>>(mlp_w1, W1T, DM, 4 * DM);
  wt_kernel<<<dim3(32, 128), 256, 0, stream>>>(mlp_w2, W2T, 4 * DM, DM);
  wt_kernel<<<dim3(1, 32), 256, 0, stream>>>(clock_w, CwT, DM, NH);
  biascat_fill<<<20, 256, 0, stream>>>(gate_b, p_b, biascat);

  ln_kernel<<<BT, 256, 0, stream>>>(x, ln1_g, ln1_b, XNb);

  // fused Q/K/V/gate/p projection: N = 5120, scatter epilogue
  gemm_bt<5><<<dim3(5 * DM / 128, BT / 128), 256, 0, stream>>>(
      XNb, WcT, biascat, nullptr, C5, nullptr, BT, 5 * DM, DM);
  gemm_bt<1><<<dim3(1, BT / 128), 256, 0, stream>>>(XNb, CwT, clock_b, nullptr, CLKr, nullptr, BT, NH, DM);

  qkprep_kernel<<<16384, 256, 0, stream>>>(Qb, Kb, Vb, Vh);

  scan_p1<<<256, 256, 0, stream>>>(Gb, Pb, cmax, gsum);
  scan_p2<<<8, 256, 0, stream>>>(cmax, gsum, pmax, gpre);
  scan_p3<<<256, 256, 0, stream>>>(Gb, Pb, CLKr, Qb, Kb, pmax, gpre, gsum);
  scan_p4<<<8, 256, 0, stream>>>(gsum, gpre);
  scan_p5<<<256, 256, 0, stream>>>(Pb, Qb, Kb, gpre, Qh, Kh);

  fattn_kernel<<<dim3(TSEQ / 64, 2 * NH), 256, 0, stream>>>(Qh, Kh, Vh, Ob);

  gemm_bt<2><<<dim3(DM / 128, BT / 128), 256, 0, stream>>>(Ob, OwT, out_b, x, X1, nullptr, BT, DM, DM);
  ln_kernel<<<BT, 256, 0, stream>>>(X1, ln2_g, ln2_b, Hb);
  gemm_bt<3><<<dim3(4 * DM / 128, BT / 128), 256, 0, stream>>>(Hb, W1T, mlp_b1, nullptr, nullptr, MID, BT, 4 * DM, DM);
  gemm_bt<2><<<dim3(DM / 128, BT / 128), 256, 0, stream>>>(MID, W2T, mlp_b2, X1, outp, nullptr, BT, DM, 4 * DM);
}

// Round 10
// 737.972 us; speedup vs baseline: 12.3492x; 1.0647x over previous
//
#include <hip/hip_runtime.h>
#include <hip/hip_bf16.h>
#include <math.h>

typedef __hip_bfloat16 bf16;
typedef __attribute__((ext_vector_type(8))) short short8;
typedef __attribute__((ext_vector_type(4))) short short4v;
typedef __attribute__((ext_vector_type(4))) float f32x4;

#define BT   4096   // B*T rows
#define DM   1024
#define NH   16
#define DH   64
#define TSEQ 2048

__device__ __forceinline__ float wave_sum(float v){
#pragma unroll
  for (int o = 32; o; o >>= 1) v += __shfl_xor(v, o);
  return v;
}

__device__ __forceinline__ float block_sum(float v){
  __shared__ float sm[4];
  v = wave_sum(v);
  __syncthreads();
  if ((threadIdx.x & 63) == 0) sm[threadIdx.x >> 6] = v;
  __syncthreads();
  return sm[0] + sm[1] + sm[2] + sm[3];
}

__device__ __forceinline__ float softplusf(float x){
  return x > 20.f ? x : log1pf(expf(x));
}

__device__ __forceinline__ short f2bf(float f){
  unsigned u = __builtin_bit_cast(unsigned, f);
  u += 0x7FFF + ((u >> 16) & 1);          // RNE; inputs finite
  return (short)(u >> 16);
}

__device__ __forceinline__ short8 ld8(const short* p){  // two 8B LDS reads
  short4v a = *(const short4v*)p;
  short4v b = *(const short4v*)(p + 4);
  short8 r;
  r[0]=a[0]; r[1]=a[1]; r[2]=a[2]; r[3]=a[3];
  r[4]=b[0]; r[5]=b[1]; r[6]=b[2]; r[7]=b[3];
  return r;
}

__device__ __forceinline__ void async16(const short* g, short* l){
  __builtin_amdgcn_global_load_lds(
      (const __attribute__((address_space(1))) void*)g,
      (__attribute__((address_space(3))) void*)l, 16, 0, 0);
}

// ---------------- weight convert+transpose: f32 [K][N] -> bf16 [N][K] ----------------
__global__ __launch_bounds__(256) void wt_kernel(const float* __restrict__ src,
    short* __restrict__ dst, int K, int N){
  __shared__ short T[32][33];
  const int tx = threadIdx.x & 31, ty = threadIdx.x >> 5;  // ty 0..7
  const int n0 = blockIdx.x << 5, k0 = blockIdx.y << 5;
#pragma unroll
  for (int r = 0; r < 4; r++){
    const int k = k0 + (ty << 2) + r;
    const int n = n0 + tx;
    T[tx][(ty << 2) + r] = (n < N) ? f2bf(src[(long)k * N + n]) : (short)0;
  }
  __syncthreads();
#pragma unroll
  for (int r = 0; r < 4; r++){
    const int n = n0 + (ty << 2) + r;
    if (n < N) dst[(long)n * K + k0 + tx] = T[(ty << 2) + r][tx];
  }
}

// ------- bias concat fill: [0..3071]=0, gate_b, p_b, clock_b (5136 entries) -------
__global__ __launch_bounds__(256) void biascat_fill(const float* __restrict__ gb,
    const float* __restrict__ pb, const float* __restrict__ cb, float* __restrict__ out){
  const int i = blockIdx.x * 256 + threadIdx.x;
  if (i >= 5136) return;
  float v = 0.f;
  if (i >= 5120) v = cb[i - 5120];
  else if (i >= 4096) v = pb[i - 4096];
  else if (i >= 3072) v = gb[i - 3072];
  out[i] = v;
}

// ---------------- LayerNorm: one block per row of 1024, bf16 out ----------------
__global__ __launch_bounds__(256) void ln_kernel(const float* __restrict__ xin,
    const float* __restrict__ g, const float* __restrict__ bb, short* __restrict__ out){
  const long row = blockIdx.x;
  const int tid = threadIdx.x;
  float v[4];
#pragma unroll
  for (int i = 0; i < 4; i++) v[i] = xin[row * DM + tid + i * 256];
  float s = block_sum(v[0] + v[1] + v[2] + v[3]);
  const float mu = s * (1.f / DM);
  float d2 = 0.f;
#pragma unroll
  for (int i = 0; i < 4; i++){ float dd = v[i] - mu; d2 = fmaf(dd, dd, d2); }
  d2 = block_sum(d2);
  const float rstd = rsqrtf(d2 * (1.f / DM) + 1e-5f);
#pragma unroll
  for (int i = 0; i < 4; i++){
    int c = tid + i * 256;
    out[row * DM + c] = f2bf(fmaf((v[i] - mu) * rstd, g[c], bb[c]));
  }
}

// ---------------- MFMA GEMM: C[M,N] = A[M,K](bf16) @ Bt[N,K]^T(bf16) + epilogue ------
// EPI: 0 Cf=v | 1 Cf=v+bias | 2 Cf=v+bias+resf | 3 Cbf=bf16(gelu(v+bias))
//      5 proj-scatter (N=5136): +bias; cols [0,5120)->C5 f32 slots (Q,K,V,G,P),
//         cols [5120,5136)->Cf slot5 row*16 layout (CLKr)
template <int EPI>
__global__ __launch_bounds__(256) void gemm_bt(
    const short* __restrict__ A, const short* __restrict__ Bt,
    const float* __restrict__ bias, const float* __restrict__ resf,
    float* __restrict__ Cf, short* __restrict__ Cbf, int M, int N, int K)
{
  __shared__ __attribute__((aligned(16))) short As[128 * 32];
  __shared__ __attribute__((aligned(16))) short Bs[128 * 32];
  const int tid = threadIdx.x;
  const int lane = tid & 63, w = tid >> 6;
  const int l16 = lane & 15, quad = lane >> 4;
  const int wm = w >> 1, wn = w & 1;
  const int bm0 = blockIdx.y << 7, bn0 = blockIdx.x << 7;

  f32x4 acc[4][4] = {};

  for (int k0 = 0; k0 < K; k0 += 32){
#pragma unroll
    for (int p = 0; p < 2; p++){
      const int lin = p * 256 + tid;        // 16B chunk index in tile
      const int r = lin >> 2, c = lin & 3;  // row 0..127, 16B chunk 0..3
      const short* ga = A + (long)(bm0 + r) * K + k0 + c * 8;
      const int rowB = min(bn0 + r, N - 1); // clamp for tail tiles
      const short* gb = Bt + (long)rowB * K + k0 + c * 8;
      async16(ga, &As[p * 2048 + (w << 9)]);
      async16(gb, &Bs[p * 2048 + (w << 9)]);
    }
    __syncthreads();
    short8 af[4], bfr[4];
#pragma unroll
    for (int i = 0; i < 4; i++){
      af[i]  = *(const short8*)&As[(wm * 64 + i * 16 + l16) * 32 + quad * 8];
      bfr[i] = *(const short8*)&Bs[(wn * 64 + i * 16 + l16) * 32 + quad * 8];
    }
#pragma unroll
    for (int i = 0; i < 4; i++)
#pragma unroll
      for (int j = 0; j < 4; j++)
        acc[i][j] = __builtin_amdgcn_mfma_f32_16x16x32_bf16(af[i], bfr[j], acc[i][j], 0, 0, 0);
    __syncthreads();
  }

#pragma unroll
  for (int i = 0; i < 4; i++){
#pragma unroll
    for (int r = 0; r < 4; r++){
      const int row = bm0 + wm * 64 + i * 16 + quad * 4 + r;
#pragma unroll
      for (int j = 0; j < 4; j++){
        const int col = bn0 + wn * 64 + j * 16 + l16;
        if (col < N){
          float v = acc[i][j][r];
          const long off = (long)row * N + col;
          if constexpr (EPI >= 1) v += bias[col];
          if constexpr (EPI == 2) v += resf[off];
          if constexpr (EPI == 3){
            v = 0.5f * v * (1.f + erff(v * 0.70710678118654752f));
            Cbf[off] = f2bf(v);
          } else if constexpr (EPI == 5){
            if (col < 5120)
              Cf[(long)(col >> 10) * 4194304 + (long)row * 1024 + (col & 1023)] = v;
            else
              Cf[20971520 + (long)row * 16 + (col - 5120)] = v;   // CLKr (slot 5)
          } else {
            Cf[off] = v;
          }
        }
      }
    }
  }
}

// ---------------- Chunked scans over T (32 chunks x 64) ----------------
// p1 also converts V f32 -> bf16 Vh (XNb overlay; XNb dead after proj GEMM)
__global__ __launch_bounds__(256) void scan_p1(float* __restrict__ G, const float* __restrict__ P,
    const float* __restrict__ Vf, short* __restrict__ Vh,
    float* __restrict__ cmax, float* __restrict__ gsum){
  const int tid = blockIdx.x * 256 + threadIdx.x;    // 65536
  const int d = tid & 63, c = (tid >> 6) & 31, bh = tid >> 11;
  const int h = bh & 15, b = bh >> 4;
  const long base = (((long)(b * TSEQ + c * 64)) * NH + h) * 64 + d;
  float mx = -1e30f, gs = 0.f;
  for (int tt = 0; tt < 64; tt++){
    const long idx = base + (long)tt * (NH * 64);
    float gj = -softplusf(G[idx]);
    G[idx] = gj;
    gs += gj;
    mx = fmaxf(mx, P[idx]);
    Vh[idx] = f2bf(Vf[idx]);
  }
  const int chain = bh * 64 + d;
  cmax[chain * 32 + c] = mx;
  gsum[chain * 32 + c] = gs;
}

__global__ void scan_p2(const float* __restrict__ cmax, const float* __restrict__ gsum,
                        float* __restrict__ pmax, float* __restrict__ gpre){
  const int chain = blockIdx.x * 256 + threadIdx.x;  // 2048
  float mx = -1e30f;
  for (int c = 0; c < 32; c++) mx = fmaxf(mx, cmax[chain * 32 + c]);
  pmax[chain] = mx;
  float run = 0.f;
  for (int c = 0; c < 32; c++){ gpre[chain * 32 + c] = run; run += gsum[chain * 32 + c]; }
}

// p3 also applies l2norm + RoPE to Q,K (wave lanes == the 64 d-values of one row)
__global__ __launch_bounds__(256) void scan_p3(const float* __restrict__ G, float* __restrict__ P,
    const float* __restrict__ CLKr, float* __restrict__ Q, float* __restrict__ K,
    const float* __restrict__ pmax, const float* __restrict__ gpre, float* __restrict__ psum){
  const int tid = blockIdx.x * 256 + threadIdx.x;
  const int d = tid & 63, c = (tid >> 6) & 31, bh = tid >> 11;
  const int h = bh & 15, b = bh >> 4;
  const int chain = bh * 64 + d;
  const long base = (((long)(b * TSEQ + c * 64)) * NH + h) * 64 + d;
  const float pm = pmax[chain];
  const float freq = expf(-(float)(d >> 1) * 0.28782313662425575f); // ln(1e4)/32
  float grun = gpre[chain * 32 + c];
  float ps = 0.f;
  for (int tt = 0; tt < 64; tt++){
    const long idx = base + (long)tt * (NH * 64);
    const int t = c * 64 + tt;
    const float th = (float)t * freq;
    const float sn = sinf(th), cn = cosf(th);
    float clk = softplusf(CLKr[(long)(b * TSEQ + t) * NH + h]);
    float pe = expf(P[idx] - pm) * clk;
    P[idx] = pe; ps += pe;
    grun += G[idx];
    float gc = expf(fminf(fmaxf(grun, -60.f), 50.f));
    {
      float q = Q[idx];
      float n = sqrtf(wave_sum(q * q));
      q = q / fmaxf(n, 1e-12f);
      float pr = __shfl_xor(q, 1);
      q = (d & 1) ? fmaf(pr, sn, q * cn) : fmaf(q, cn, -pr * sn);
      Q[idx] = q * gc;
    }
    {
      float k = K[idx];
      float n = sqrtf(wave_sum(k * k));
      k = k / fmaxf(n, 1e-12f);
      float pr = __shfl_xor(k, 1);
      k = (d & 1) ? fmaf(pr, sn, k * cn) : fmaf(k, cn, -pr * sn);
      K[idx] = k / (gc + 1e-8f);
    }
  }
  psum[chain * 32 + c] = ps;
}

__global__ void scan_p4(const float* __restrict__ psum, float* __restrict__ ppre){
  const int chain = blockIdx.x * 256 + threadIdx.x;
  float run = 0.f;
  for (int c = 0; c < 32; c++){ ppre[chain * 32 + c] = run; run += psum[chain * 32 + c]; }
}

// final scan: emits bf16 Qh (pre-scaled by 0.125) and bf16 Kh (V f32 dead by now)
__global__ __launch_bounds__(256) void scan_p5(const float* __restrict__ P, const float* __restrict__ Q,
    const float* __restrict__ K, const float* __restrict__ ppre,
    short* __restrict__ Qh, short* __restrict__ Kh){
  const int tid = blockIdx.x * 256 + threadIdx.x;
  const int d = tid & 63, c = (tid >> 6) & 31, bh = tid >> 11;
  const int h = bh & 15, b = bh >> 4;
  const int chain = bh * 64 + d;
  const long base = (((long)(b * TSEQ + c * 64)) * NH + h) * 64 + d;
  float cs = ppre[chain * 32 + c];
  for (int tt = 0; tt < 64; tt++){
    const long idx = base + (long)tt * (NH * 64);
    float pe = P[idx];
    cs += pe;
    Qh[idx] = f2bf(Q[idx] / (cs + 1e-8f) * 0.125f);
    Kh[idx] = f2bf(K[idx] * pe);
  }
}

// ------- MFMA flash attention: fixed-m softmax (|s|<=0.125 < 0.25), deferred l,
//         register prefetch of next K/V tile, 64-key tiles, bf16 in/out -------
__global__ __launch_bounds__(256) void fattn_kernel(const short* __restrict__ Qh,
    const short* __restrict__ Kh, const short* __restrict__ Vh, short* __restrict__ O){
  __shared__ __attribute__((aligned(16))) short Ks[64][72];   // [key][d]
  __shared__ __attribute__((aligned(16))) short Vt[64][68];   // [d][key]
  __shared__ __attribute__((aligned(16))) short Ps[4][16][72];
  const int tid  = threadIdx.x;
  const int lane = tid & 63, w = tid >> 6;
  const int quad = lane >> 4, l16 = lane & 15;
  const int bh = blockIdx.y, h = bh & 15, b = bh >> 4;
  const int qt = (int)(gridDim.x - 1 - blockIdx.x);   // heavy blocks first
  const int q0  = qt << 6;
  const int qw0 = q0 + w * 16;
  const long strideT = NH * DH;
  const long base_bh = ((long)b * TSEQ * NH + h) * DH;

  const short* qp = Qh + base_bh + (long)(qw0 + l16) * strideT + quad * 8;
  const short8 qa0 = *(const short8*)qp;
  const short8 qa1 = *(const short8*)(qp + 32);

  f32x4 oacc[4] = {{0,0,0,0},{0,0,0,0},{0,0,0,0},{0,0,0,0}};
  float lpart[4] = {0.f,0.f,0.f,0.f};    // per-lane partial row sums (fixed m)

  const int krow = tid >> 2, kcol = (tid & 3) << 4;  // K staging: 64 rows x 64 shorts
  const int vkey = tid & 63, vd0 = (tid >> 6) << 4;  // V staging (transpose)
  const short* kbase = Kh + base_bh + (long)krow * strideT + kcol;
  const short* vbase = Vh + base_bh + (long)vkey * strideT + vd0;

  // prefetch tile 0 into registers
  short8 kr0 = *(const short8*)kbase;
  short8 kr1 = *(const short8*)(kbase + 8);
  short8 vr0 = *(const short8*)vbase;
  short8 vr1 = *(const short8*)(vbase + 8);

  const int ntiles = qt + 1;
  for (int t = 0; t < ntiles; t++){
    // commit prefetched tile to LDS
    *(short8*)&Ks[krow][kcol]     = kr0;
    *(short8*)&Ks[krow][kcol + 8] = kr1;
#pragma unroll
    for (int j = 0; j < 8; j++) Vt[vd0 + j][vkey] = vr0[j];
#pragma unroll
    for (int j = 0; j < 8; j++) Vt[vd0 + 8 + j][vkey] = vr1[j];
    __syncthreads();
    // issue next tile's loads (overlap with compute)
    if (t + 1 < ntiles){
      const long off = (long)(t + 1) * (64 * strideT);
      kr0 = *(const short8*)(kbase + off);
      kr1 = *(const short8*)(kbase + off + 8);
      vr0 = *(const short8*)(vbase + off);
      vr1 = *(const short8*)(vbase + off + 8);
    }
    const int kt0 = t << 6;
    // ---- S = Q K^T ----
    f32x4 c[4] = {{0,0,0,0},{0,0,0,0},{0,0,0,0},{0,0,0,0}};
#pragma unroll
    for (int kg = 0; kg < 4; kg++){
      const short8 b0 = ld8(&Ks[kg * 16 + l16][quad * 8]);
      const short8 b1 = ld8(&Ks[kg * 16 + l16][32 + quad * 8]);
      c[kg] = __builtin_amdgcn_mfma_f32_16x16x32_bf16(qa0, b0, c[kg], 0, 0, 0);
      c[kg] = __builtin_amdgcn_mfma_f32_16x16x32_bf16(qa1, b1, c[kg], 0, 0, 0);
    }
    // ---- causal mask (diagonal tiles only) ----
    if (kt0 + 63 > qw0){
#pragma unroll
      for (int kg = 0; kg < 4; kg++)
#pragma unroll
        for (int r = 0; r < 4; r++){
          const int qq = qw0 + quad * 4 + r;
          if (kt0 + kg * 16 + l16 > qq) c[kg][r] = -1e30f;
        }
    }
    // ---- fixed-m softmax: p = exp(s - 0.25); accumulate per-lane l partials ----
#pragma unroll
    for (int kg = 0; kg < 4; kg++)
#pragma unroll
      for (int r = 0; r < 4; r++) c[kg][r] = __expf(c[kg][r] - 0.25f);
#pragma unroll
    for (int r = 0; r < 4; r++)
      lpart[r] += (c[0][r] + c[1][r]) + (c[2][r] + c[3][r]);
    // ---- P -> LDS (C-layout) -> A-frags (same-wave round trip, no barrier) ----
#pragma unroll
    for (int kg = 0; kg < 4; kg++)
#pragma unroll
      for (int r = 0; r < 4; r++)
        Ps[w][quad * 4 + r][kg * 16 + l16] = f2bf(c[kg][r]);
    const short8 pa0 = ld8(&Ps[w][l16][quad * 8]);
    const short8 pa1 = ld8(&Ps[w][l16][32 + quad * 8]);
    // ---- O += P V ----
#pragma unroll
    for (int f = 0; f < 4; f++){
      const short8 vb0 = ld8(&Vt[f * 16 + l16][quad * 8]);
      const short8 vb1 = ld8(&Vt[f * 16 + l16][32 + quad * 8]);
      oacc[f] = __builtin_amdgcn_mfma_f32_16x16x32_bf16(pa0, vb0, oacc[f], 0, 0, 0);
      oacc[f] = __builtin_amdgcn_mfma_f32_16x16x32_bf16(pa1, vb1, oacc[f], 0, 0, 0);
    }
    __syncthreads();
  }
  // ---- epilogue: reduce l partials across the 16 col-lanes, scale, store ----
#pragma unroll
  for (int r = 0; r < 4; r++){
    float l = lpart[r];
#pragma unroll
    for (int o = 1; o <= 8; o <<= 1) l += __shfl_xor(l, o);
    const float inv = 1.f / l;
    const long row = base_bh + (long)(qw0 + quad * 4 + r) * strideT + l16;
#pragma unroll
    for (int f = 0; f < 4; f++) O[row + f * 16] = f2bf(oacc[f][r] * inv);
  }
}

extern "C" void kernel_launch(void* const* d_in, const int* in_sizes, int n_in,
                              void* d_out, int out_size, void* d_ws, size_t ws_size,
                              hipStream_t stream){
  const float* x       = (const float*)d_in[0];
  const float* Wq      = (const float*)d_in[1];
  const float* Wk      = (const float*)d_in[2];
  const float* Wv      = (const float*)d_in[3];
  const float* gate_w  = (const float*)d_in[4];
  const float* gate_b  = (const float*)d_in[5];
  const float* p_w     = (const float*)d_in[6];
  const float* p_b     = (const float*)d_in[7];
  const float* out_w   = (const float*)d_in[8];
  const float* out_b   = (const float*)d_in[9];
  const float* clock_w = (const float*)d_in[10];
  const float* clock_b = (const float*)d_in[11];
  const float* ln1_g   = (const float*)d_in[12];
  const float* ln1_b   = (const float*)d_in[13];
  const float* ln2_g   = (const float*)d_in[14];
  const float* ln2_b   = (const float*)d_in[15];
  const float* mlp_w1  = (const float*)d_in[16];
  const float* mlp_b1  = (const float*)d_in[17];
  const float* mlp_w2  = (const float*)d_in[18];
  const float* mlp_b2  = (const float*)d_in[19];
  float* outp = (float*)d_out;

  // ---- workspace layout (round-8-proven liveness) ----
  float* ws   = (float*)d_ws;
  float* C5   = ws;                     // slots 0..4 f32: Qb,Kb,Vf,Gb,Pb
  float* Qb   = ws;
  float* Kb   = ws + 4194304;
  float* Vf   = ws + 8388608;
  float* Gb   = ws + 12582912;
  float* Pb   = ws + 16777216;          // later X1
  float* CLKr = ws + 20971520;          // slot 5 (row*16 layout)
  float* cmax = CLKr + 65536;
  float* gsum = cmax + 65536;           // psum
  float* gpre = gsum + 65536;           // ppre
  float* pmax = gpre + 65536;
  float* biascat = cmax;                // disjoint lifetime with cmax
  short* sb   = (short*)(ws + 21235712);
  short* XNb  = sb;                     // 4M shorts (LN1 out); Vh overlay after proj
  short* Vh   = sb;                     //   written by scan_p1 (XNb dead by then)
  short* WcT  = sb + 4194304;           // concat [5136][1024] bf16 (q,k,v,gate,p,clock)
  short* OwT  = WcT + 5260288;          // 1M
  short* W1T  = OwT + 1048576;          // 4M [4096][1024]
  short* W2T  = W1T + 4194304;          // 4M [1024][4096]
  // overlays of the V f32 slot [8388608, 12582912) — written in scan_p5, V f32 dead:
  short* Qh  = (short*)(ws + 8388608);            // 8MB
  short* Kh  = (short*)(ws + 8388608 + 2097152);  // 8MB
  // other overlays:
  short* MID = (short*)ws;                        // 16M shorts over Qb+Kb
  short* Ob  = (short*)(ws + 12582912);           // over dead Gb (first 8MB)
  short* Hb  = (short*)(ws + 12582912 + 2097152); // over dead Gb (second 8MB)
  float* X1  = Pb;

  // ---- weight convert+transpose (bf16, [N][K]) ----
  wt_kernel<<<dim3(32, 32), 256, 0, stream>>>(Wq,     WcT,               DM, DM);
  wt_kernel<<<dim3(32, 32), 256, 0, stream>>>(Wk,     WcT + 1048576,     DM, DM);
  wt_kernel<<<dim3(32, 32), 256, 0, stream>>>(Wv,     WcT + 2097152,     DM, DM);
  wt_kernel<<<dim3(32, 32), 256, 0, stream>>>(gate_w, WcT + 3145728,     DM, DM);
  wt_kernel<<<dim3(32, 32), 256, 0, stream>>>(p_w,    WcT + 4194304,     DM, DM);
  wt_kernel<<<dim3(1, 32), 256, 0, stream>>>(clock_w, WcT + 5242880,     DM, NH);
  wt_kernel<<<dim3(32, 32), 256, 0, stream>>>(out_w,  OwT,               DM, DM);
  wt_kernel<<<dim3(128, 32), 256, 0, stream>>>(mlp_w1, W1T, DM, 4 * DM);
  wt_kernel<<<dim3(32, 128), 256, 0, stream>>>(mlp_w2, W2T, 4 * DM, DM);
  biascat_fill<<<21, 256, 0, stream>>>(gate_b, p_b, clock_b, biascat);

  ln_kernel<<<BT, 256, 0, stream>>>(x, ln1_g, ln1_b, XNb);

  // fused Q/K/V/gate/p/clock projection: N = 5136, scatter epilogue
  gemm_bt<5><<<dim3(41, BT / 128), 256, 0, stream>>>(
      XNb, WcT, biascat, nullptr, C5, nullptr, BT, 5136, DM);

  scan_p1<<<256, 256, 0, stream>>>(Gb, Pb, Vf, Vh, cmax, gsum);
  scan_p2<<<8, 256, 0, stream>>>(cmax, gsum, pmax, gpre);
  scan_p3<<<256, 256, 0, stream>>>(Gb, Pb, CLKr, Qb, Kb, pmax, gpre, gsum);
  scan_p4<<<8, 256, 0, stream>>>(gsum, gpre);
  scan_p5<<<256, 256, 0, stream>>>(Pb, Qb, Kb, gpre, Qh, Kh);

  fattn_kernel<<<dim3(TSEQ / 64, 2 * NH), 256, 0, stream>>>(Qh, Kh, Vh, Ob);

  gemm_bt<2><<<dim3(DM / 128, BT / 128), 256, 0, stream>>>(Ob, OwT, out_b, x, X1, nullptr, BT, DM, DM);
  ln_kernel<<<BT, 256, 0, stream>>>(X1, ln2_g, ln2_b, Hb);
  gemm_bt<3><<<dim3(4 * DM / 128, BT / 128), 256, 0, stream>>>(Hb, W1T, mlp_b1, nullptr, nullptr, MID, BT, 4 * DM, DM);
  gemm_bt<2><<<dim3(DM / 128, BT / 128), 256, 0, stream>>>(MID, W2T, mlp_b2, X1, outp, nullptr, BT, DM, 4 * DM);
}